// Round 1
// baseline (3130.257 us; speedup 1.0000x reference)
//
#include <hip/hip_runtime.h>

#define Vv 32000
#define Hh 256
#define Hx2 512
#define HALFd 128
#define Bb 64
#define Ll 2048

// ---------------- Encoder: e=embed[seq]; u=relu(e@W1+b1); f=u@W2+b2;
// x=e+f; h=LN(x)*gamma+beta; p = h@Wp + bp  ----------------
// One block per 32 tokens, 256 threads, everything f32 in LDS.
__global__ __launch_bounds__(256) void enc_kernel(
    const int* __restrict__ seq, const float* __restrict__ embed,
    const float* __restrict__ W1, const float* __restrict__ b1,
    const float* __restrict__ W2, const float* __restrict__ b2,
    const float* __restrict__ gamma, const float* __restrict__ beta,
    const float* __restrict__ Wp, const float* __restrict__ bp,
    float* __restrict__ p_out)
{
    __shared__ float sE[32 * 260];   // e, then x, then h (pad 256->260)
    __shared__ float sU[32 * 516];   // relu output (pad 512->516)
    __shared__ float sW[8192];       // weight staging (32 KB)

    const int tid = threadIdx.x;
    const int n0 = blockIdx.x * 32;

    // ---- load E tile: 32 tokens x 256 f32 (gather) ----
    #pragma unroll
    for (int r = 0; r < 8; ++r) {
        int f4 = r * 256 + tid;      // 0..2047 float4s
        int tok = f4 >> 6;
        int c4  = f4 & 63;
        int vrow = seq[n0 + tok];
        float4 v = ((const float4*)embed)[(size_t)vrow * 64 + c4];
        *(float4*)&sE[tok * 260 + c4 * 4] = v;
    }

    // ---- GEMM1: U = relu(E @ W1 + b1), 32x512 ----
    {
        const int tr = tid >> 5;      // 0..7  -> tokens {tr, tr+8, tr+16, tr+24}
        const int tc = tid & 31;      // 0..31 -> cols tc*16 .. +15
        float acc[4][16];
        #pragma unroll
        for (int i = 0; i < 4; ++i)
            #pragma unroll
            for (int j = 0; j < 16; ++j) acc[i][j] = 0.f;

        for (int k0 = 0; k0 < Hh; k0 += 16) {
            __syncthreads();
            #pragma unroll
            for (int r = 0; r < 8; ++r) {
                int f4 = r * 256 + tid;
                ((float4*)sW)[f4] = ((const float4*)(W1 + (size_t)k0 * Hx2))[f4];
            }
            __syncthreads();
            #pragma unroll
            for (int kk = 0; kk < 16; ++kk) {
                float e0 = sE[(tr     ) * 260 + k0 + kk];
                float e1 = sE[(tr +  8) * 260 + k0 + kk];
                float e2 = sE[(tr + 16) * 260 + k0 + kk];
                float e3 = sE[(tr + 24) * 260 + k0 + kk];
                float w[16];
                #pragma unroll
                for (int q = 0; q < 4; ++q)
                    *(float4*)&w[q * 4] = *(const float4*)&sW[kk * 512 + tc * 16 + q * 4];
                #pragma unroll
                for (int j = 0; j < 16; ++j) {
                    acc[0][j] = fmaf(e0, w[j], acc[0][j]);
                    acc[1][j] = fmaf(e1, w[j], acc[1][j]);
                    acc[2][j] = fmaf(e2, w[j], acc[2][j]);
                    acc[3][j] = fmaf(e3, w[j], acc[3][j]);
                }
            }
        }
        float bb[16];
        #pragma unroll
        for (int q = 0; q < 4; ++q)
            *(float4*)&bb[q * 4] = *(const float4*)&b1[tc * 16 + q * 4];
        #pragma unroll
        for (int i = 0; i < 4; ++i) {
            int tok = tr + i * 8;
            #pragma unroll
            for (int j = 0; j < 16; ++j)
                sU[tok * 516 + tc * 16 + j] = fmaxf(acc[i][j] + bb[j], 0.f);
        }
    }

    // ---- GEMM2: F = U @ W2 + b2 ; x = E + F (in place into sE) ----
    {
        const int tr = tid >> 5;      // tokens {tr, tr+8, tr+16, tr+24}
        const int tc = tid & 31;      // cols tc*8 .. +7
        float acc[4][8];
        #pragma unroll
        for (int i = 0; i < 4; ++i)
            #pragma unroll
            for (int j = 0; j < 8; ++j) acc[i][j] = 0.f;

        for (int k0 = 0; k0 < Hx2; k0 += 32) {
            __syncthreads();
            #pragma unroll
            for (int r = 0; r < 8; ++r) {
                int f4 = r * 256 + tid;
                ((float4*)sW)[f4] = ((const float4*)(W2 + (size_t)k0 * Hh))[f4];
            }
            __syncthreads();
            #pragma unroll
            for (int kk = 0; kk < 32; ++kk) {
                float u0 = sU[(tr     ) * 516 + k0 + kk];
                float u1 = sU[(tr +  8) * 516 + k0 + kk];
                float u2 = sU[(tr + 16) * 516 + k0 + kk];
                float u3 = sU[(tr + 24) * 516 + k0 + kk];
                float w[8];
                *(float4*)&w[0] = *(const float4*)&sW[kk * 256 + tc * 8];
                *(float4*)&w[4] = *(const float4*)&sW[kk * 256 + tc * 8 + 4];
                #pragma unroll
                for (int j = 0; j < 8; ++j) {
                    acc[0][j] = fmaf(u0, w[j], acc[0][j]);
                    acc[1][j] = fmaf(u1, w[j], acc[1][j]);
                    acc[2][j] = fmaf(u2, w[j], acc[2][j]);
                    acc[3][j] = fmaf(u3, w[j], acc[3][j]);
                }
            }
        }
        float bb[8];
        *(float4*)&bb[0] = *(const float4*)&b2[tc * 8];
        *(float4*)&bb[4] = *(const float4*)&b2[tc * 8 + 4];
        #pragma unroll
        for (int i = 0; i < 4; ++i) {
            int tok = tr + i * 8;
            #pragma unroll
            for (int j = 0; j < 8; ++j) {
                int c = tc * 8 + j;
                sE[tok * 260 + c] += acc[i][j] + bb[j];
            }
        }
    }
    __syncthreads();

    // ---- LayerNorm in place (8 lanes per token) ----
    {
        const int tok = tid >> 3, part = tid & 7;
        float s1 = 0.f, s2 = 0.f;
        #pragma unroll
        for (int q = 0; q < 8; ++q) {
            float4 v = *(const float4*)&sE[tok * 260 + part * 32 + q * 4];
            s1 += v.x + v.y + v.z + v.w;
            s2 += v.x * v.x + v.y * v.y + v.z * v.z + v.w * v.w;
        }
        s1 += __shfl_xor(s1, 1); s2 += __shfl_xor(s2, 1);
        s1 += __shfl_xor(s1, 2); s2 += __shfl_xor(s2, 2);
        s1 += __shfl_xor(s1, 4); s2 += __shfl_xor(s2, 4);
        float mu   = s1 * (1.f / 256.f);
        float var  = s2 * (1.f / 256.f) - mu * mu;
        float rstd = rsqrtf(var + 1e-5f);
        #pragma unroll
        for (int q = 0; q < 8; ++q) {
            int c = part * 32 + q * 4;
            float4 v = *(const float4*)&sE[tok * 260 + c];
            float4 g  = *(const float4*)&gamma[c];
            float4 bt = *(const float4*)&beta[c];
            v.x = (v.x - mu) * rstd * g.x + bt.x;
            v.y = (v.y - mu) * rstd * g.y + bt.y;
            v.z = (v.z - mu) * rstd * g.z + bt.z;
            v.w = (v.w - mu) * rstd * g.w + bt.w;
            *(float4*)&sE[tok * 260 + c] = v;
        }
    }

    // ---- GEMM3: P = h @ Wp + bp, 32x128 -> global ----
    {
        const int tr = tid >> 4;     // 0..15 -> tokens {tr, tr+16}
        const int tc = tid & 15;     // 0..15 -> cols tc*8 .. +7
        float acc[2][8];
        #pragma unroll
        for (int i = 0; i < 2; ++i)
            #pragma unroll
            for (int j = 0; j < 8; ++j) acc[i][j] = 0.f;

        for (int k0 = 0; k0 < Hh; k0 += 32) {
            __syncthreads();
            #pragma unroll
            for (int r = 0; r < 4; ++r) {
                int f4 = r * 256 + tid;
                ((float4*)sW)[f4] = ((const float4*)(Wp + (size_t)k0 * HALFd))[f4];
            }
            __syncthreads();
            #pragma unroll
            for (int kk = 0; kk < 32; ++kk) {
                float h0 = sE[(tr     ) * 260 + k0 + kk];
                float h1 = sE[(tr + 16) * 260 + k0 + kk];
                float w[8];
                *(float4*)&w[0] = *(const float4*)&sW[kk * 128 + tc * 8];
                *(float4*)&w[4] = *(const float4*)&sW[kk * 128 + tc * 8 + 4];
                #pragma unroll
                for (int j = 0; j < 8; ++j) {
                    acc[0][j] = fmaf(h0, w[j], acc[0][j]);
                    acc[1][j] = fmaf(h1, w[j], acc[1][j]);
                }
            }
        }
        float bb[8];
        *(float4*)&bb[0] = *(const float4*)&bp[tc * 8];
        *(float4*)&bb[4] = *(const float4*)&bp[tc * 8 + 4];
        #pragma unroll
        for (int i = 0; i < 2; ++i) {
            int tok = tr + i * 16;
            float4 v0 = make_float4(acc[i][0] + bb[0], acc[i][1] + bb[1],
                                    acc[i][2] + bb[2], acc[i][3] + bb[3]);
            float4 v1 = make_float4(acc[i][4] + bb[4], acc[i][5] + bb[5],
                                    acc[i][6] + bb[6], acc[i][7] + bb[7]);
            size_t off = (size_t)(n0 + tok) * HALFd + tc * 8;
            *(float4*)&p_out[off]     = v0;
            *(float4*)&p_out[off + 4] = v1;
        }
    }
}

// ---------------- Delta-rule scan: row-parallel over B*HALF rows.
// Block = (batch, 32 rows); 8 lanes per row, 16 cols/lane, M row in VGPRs.
__global__ __launch_bounds__(256) void scan_kernel(
    const float* __restrict__ p, float* __restrict__ cs)
{
    const int b     = blockIdx.x >> 2;
    const int g     = blockIdx.x & 3;
    const int lane8 = threadIdx.x & 7;
    const int row   = g * 32 + (threadIdx.x >> 3);
    const int col0  = lane8 * 16;
    const float* pb = p + (size_t)b * Ll * HALFd;

    float M[16];
    #pragma unroll
    for (int j = 0; j < 16; ++j) M[j] = 0.f;

    // register double-buffer of the k row (prefetch one step ahead)
    float4 n0, n1, n2, n3; float nki;
    {
        const float* kr = pb;
        n0 = *(const float4*)(kr + col0);
        n1 = *(const float4*)(kr + col0 + 4);
        n2 = *(const float4*)(kr + col0 + 8);
        n3 = *(const float4*)(kr + col0 + 12);
        nki = kr[row];
    }

    for (int t = 0; t < Ll - 1; ++t) {
        float k[16];
        *(float4*)&k[0]  = n0; *(float4*)&k[4]  = n1;
        *(float4*)&k[8]  = n2; *(float4*)&k[12] = n3;
        float ki = nki;
        // prefetch next row (t+1 <= Ll-1 always; last prefetch = query row)
        const float* kr = pb + (size_t)(t + 1) * HALFd;
        n0 = *(const float4*)(kr + col0);
        n1 = *(const float4*)(kr + col0 + 4);
        n2 = *(const float4*)(kr + col0 + 8);
        n3 = *(const float4*)(kr + col0 + 12);
        nki = kr[row];

        float d0 = 0, d1 = 0, d2 = 0, d3 = 0;
        float q0 = 0, q1 = 0, q2 = 0, q3 = 0;
        #pragma unroll
        for (int j = 0; j < 4; ++j) {
            d0 = fmaf(M[j],      k[j],      d0);
            d1 = fmaf(M[4 + j],  k[4 + j],  d1);
            d2 = fmaf(M[8 + j],  k[8 + j],  d2);
            d3 = fmaf(M[12 + j], k[12 + j], d3);
            q0 = fmaf(k[j],      k[j],      q0);
            q1 = fmaf(k[4 + j],  k[4 + j],  q1);
            q2 = fmaf(k[8 + j],  k[8 + j],  q2);
            q3 = fmaf(k[12 + j], k[12 + j], q3);
        }
        float dot = (d0 + d1) + (d2 + d3);
        float qq  = (q0 + q1) + (q2 + q3);
        dot += __shfl_xor(dot, 1); qq += __shfl_xor(qq, 1);
        dot += __shfl_xor(dot, 2); qq += __shfl_xor(qq, 2);
        dot += __shfl_xor(dot, 4); qq += __shfl_xor(qq, 4);

        float dvs = ki - dot / (qq + 1e-6f);
        #pragma unroll
        for (int j = 0; j < 16; ++j) M[j] = fmaf(dvs, k[j], M[j]);
    }

    // query row (t = Ll-1) already sits in n0..n3
    float k[16];
    *(float4*)&k[0]  = n0; *(float4*)&k[4]  = n1;
    *(float4*)&k[8]  = n2; *(float4*)&k[12] = n3;
    float d0 = 0, d1 = 0, d2 = 0, d3 = 0;
    #pragma unroll
    for (int j = 0; j < 4; ++j) {
        d0 = fmaf(M[j],      k[j],      d0);
        d1 = fmaf(M[4 + j],  k[4 + j],  d1);
        d2 = fmaf(M[8 + j],  k[8 + j],  d2);
        d3 = fmaf(M[12 + j], k[12 + j], d3);
    }
    float dot = (d0 + d1) + (d2 + d3);
    dot += __shfl_xor(dot, 1);
    dot += __shfl_xor(dot, 2);
    dot += __shfl_xor(dot, 4);
    if (lane8 == 0) cs[b * HALFd + row] = dot;
}

// ---------------- out = cs @ Wo + bo : [64,128]@[128,32000] ----------------
__global__ __launch_bounds__(256) void out_kernel(
    const float* __restrict__ cs, const float* __restrict__ Wo,
    const float* __restrict__ bo, float* __restrict__ out)
{
    __shared__ float sC[64 * 128];
    const int tid = threadIdx.x;
    #pragma unroll
    for (int r = 0; r < 8; ++r)
        ((float4*)sC)[r * 256 + tid] = ((const float4*)cs)[r * 256 + tid];
    __syncthreads();

    const int j = blockIdx.x * 256 + tid;   // column (vocab id)
    float acc[64];
    #pragma unroll
    for (int r = 0; r < 64; ++r) acc[r] = 0.f;

    for (int k0 = 0; k0 < 128; k0 += 4) {
        float w0 = Wo[(size_t)(k0 + 0) * Vv + j];
        float w1 = Wo[(size_t)(k0 + 1) * Vv + j];
        float w2 = Wo[(size_t)(k0 + 2) * Vv + j];
        float w3 = Wo[(size_t)(k0 + 3) * Vv + j];
        #pragma unroll
        for (int r = 0; r < 64; ++r) {
            float4 c = *(const float4*)&sC[r * 128 + k0];
            acc[r] = fmaf(c.x, w0, fmaf(c.y, w1, fmaf(c.z, w2, fmaf(c.w, w3, acc[r]))));
        }
    }
    float bj = bo[j];
    #pragma unroll
    for (int r = 0; r < 64; ++r)
        out[(size_t)r * Vv + j] = acc[r] + bj;
}

extern "C" void kernel_launch(void* const* d_in, const int* in_sizes, int n_in,
                              void* d_out, int out_size, void* d_ws, size_t ws_size,
                              hipStream_t stream)
{
    const int*   seq   = (const int*)  d_in[0];
    const float* embed = (const float*)d_in[1];
    const float* W1    = (const float*)d_in[2];
    const float* b1    = (const float*)d_in[3];
    const float* W2    = (const float*)d_in[4];
    const float* b2    = (const float*)d_in[5];
    const float* gamma = (const float*)d_in[6];
    const float* beta  = (const float*)d_in[7];
    const float* Wp    = (const float*)d_in[8];
    const float* bp    = (const float*)d_in[9];
    const float* Wo    = (const float*)d_in[10];
    const float* bo    = (const float*)d_in[11];
    float* out = (float*)d_out;

    float* p  = (float*)d_ws;                         // [B*L, 128] f32 = 64 MB
    float* cs = p + (size_t)Bb * Ll * HALFd;          // [B, 128]

    enc_kernel<<<(Bb * Ll) / 32, 256, 0, stream>>>(seq, embed, W1, b1, W2, b2,
                                                   gamma, beta, Wp, bp, p);
    scan_kernel<<<Bb * 4, 256, 0, stream>>>(p, cs);
    out_kernel<<<Vv / 256, 256, 0, stream>>>(cs, Wo, bo, out);
}

// Round 2
// 610.374 us; speedup vs baseline: 5.1284x; 5.1284x over previous
//
#include <hip/hip_runtime.h>

#define Vv 32000
#define Ll 2048

typedef __bf16 bf16x8 __attribute__((ext_vector_type(8)));
typedef float  f32x4  __attribute__((ext_vector_type(4)));

__device__ __forceinline__ unsigned short f2bf(float f) {
    unsigned u = __builtin_bit_cast(unsigned, f);
    u += 0x7fffu + ((u >> 16) & 1u);
    return (unsigned short)(u >> 16);
}
__device__ __forceinline__ float bf2f(unsigned short s) {
    unsigned u = (unsigned)s << 16;
    return __builtin_bit_cast(float, u);
}
__device__ __forceinline__ f32x4 cvt4(ushort4 v) {
    f32x4 r; r.x = bf2f(v.x); r.y = bf2f(v.y); r.z = bf2f(v.z); r.w = bf2f(v.w);
    return r;
}
__device__ __forceinline__ void unpk8(uint4 v, float* o) {
    o[0] = bf2f((unsigned short)(v.x & 0xffff)); o[1] = bf2f((unsigned short)(v.x >> 16));
    o[2] = bf2f((unsigned short)(v.y & 0xffff)); o[3] = bf2f((unsigned short)(v.y >> 16));
    o[4] = bf2f((unsigned short)(v.z & 0xffff)); o[5] = bf2f((unsigned short)(v.z >> 16));
    o[6] = bf2f((unsigned short)(v.w & 0xffff)); o[7] = bf2f((unsigned short)(v.w >> 16));
}

#define MFMA(a, b, c) __builtin_amdgcn_mfma_f32_16x16x32_bf16(a, b, c, 0, 0, 0)
#define GLL16(gsrc, ldst)                                                    \
    __builtin_amdgcn_global_load_lds(                                        \
        (const __attribute__((address_space(1))) void*)(gsrc),               \
        (__attribute__((address_space(3))) void*)(ldst), 16, 0, 0)

// ---------------- prep: transpose W1/W2/Wp to bf16 [N][K] ----------------
__global__ __launch_bounds__(256) void prep_kernel(
    const float* __restrict__ W1, const float* __restrict__ W2,
    const float* __restrict__ Wp, unsigned short* __restrict__ W1T,
    unsigned short* __restrict__ W2T, unsigned short* __restrict__ WpT)
{
    int idx = blockIdx.x * 256 + threadIdx.x;   // pair index
    if (idx < 65536) {                           // W1T [512][256] <- W1 [256][512]
        int e0 = idx * 2, n = e0 >> 8, k = e0 & 255;
        unsigned lo = f2bf(W1[(size_t)k * 512 + n]);
        unsigned hi = f2bf(W1[(size_t)(k + 1) * 512 + n]);
        ((unsigned*)W1T)[idx] = lo | (hi << 16);
    } else if (idx < 131072) {                   // W2T [256][512] <- W2 [512][256]
        int i = idx - 65536, e0 = i * 2, n = e0 >> 9, k = e0 & 511;
        unsigned lo = f2bf(W2[(size_t)k * 256 + n]);
        unsigned hi = f2bf(W2[(size_t)(k + 1) * 256 + n]);
        ((unsigned*)W2T)[i] = lo | (hi << 16);
    } else {                                     // WpT [128][256] <- Wp [256][128]
        int i = idx - 131072, e0 = i * 2, n = e0 >> 8, k = e0 & 255;
        unsigned lo = f2bf(Wp[(size_t)k * 128 + n]);
        unsigned hi = f2bf(Wp[(size_t)(k + 1) * 128 + n]);
        ((unsigned*)WpT)[i] = lo | (hi << 16);
    }
}

// ---------------- fused MFMA encoder ----------------
// 512 threads = 8 waves (2 M-groups x 4 N-groups), 64 tokens/block.
__global__ __launch_bounds__(512, 4) void enc_kernel(
    const int* __restrict__ seq, const float* __restrict__ embed,
    const unsigned short* __restrict__ W1T, const float* __restrict__ b1,
    const unsigned short* __restrict__ W2T, const float* __restrict__ b2,
    const float* __restrict__ gamma, const float* __restrict__ beta,
    const unsigned short* __restrict__ WpT, const float* __restrict__ bp,
    unsigned short* __restrict__ p_bf)
{
    __shared__ char sE[64 * 512];      // bf16 [64][256], XOR-swizzled (e, then h)
    __shared__ char sU[64 * 256];      // bf16 [64][128], swizzled (U chunk) / plain (p stage)
    __shared__ float sPart[64][4][2];
    __shared__ float sMR[64][2];

    const int tid  = threadIdx.x;
    const int lane = tid & 63;
    const int w    = tid >> 6;
    const int wm   = w >> 2;           // 0..1
    const int wn   = w & 3;            // 0..3
    const int l15  = lane & 15;
    const int lk   = lane >> 4;        // 0..3
    const int n0   = blockIdx.x * 64;
    const int r0   = wm * 32;
    const int swl  = (l15 & 7) << 4;   // A-frag row swizzle (row&7 == l15&7)

    // ---- gather: embed rows -> sE bf16 (swizzled via pre-swizzled source) ----
    #pragma unroll
    for (int cc = 0; cc < 4; ++cc) {
        int c = cc * 512 + tid;          // 0..2047 16B-chunks
        int row  = c >> 5;
        int slot = (c & 31) << 4;
        int kbs  = slot ^ ((row & 7) << 4);
        int vrow = seq[n0 + row];
        const float* src = embed + (size_t)vrow * 256 + (kbs >> 1);
        float4 a = *(const float4*)src;
        float4 b = *(const float4*)(src + 4);
        uint4 pk;
        pk.x = (unsigned)f2bf(a.x) | ((unsigned)f2bf(a.y) << 16);
        pk.y = (unsigned)f2bf(a.z) | ((unsigned)f2bf(a.w) << 16);
        pk.z = (unsigned)f2bf(b.x) | ((unsigned)f2bf(b.y) << 16);
        pk.w = (unsigned)f2bf(b.z) | ((unsigned)f2bf(b.w) << 16);
        *(uint4*)(sE + row * 512 + slot) = pk;
    }
    __syncthreads();

    f32x4 acc2[2][4];
    #pragma unroll
    for (int i = 0; i < 2; ++i)
        #pragma unroll
        for (int j = 0; j < 4; ++j) acc2[i][j] = (f32x4){0.f, 0.f, 0.f, 0.f};

    #pragma unroll 1
    for (int c = 0; c < 4; ++c) {
        // ---- GEMM1 chunk: cols [c*128, c*128+128) ----
        f32x4 acc1[2][2];
        acc1[0][0] = acc1[0][1] = acc1[1][0] = acc1[1][1] = (f32x4){0.f, 0.f, 0.f, 0.f};
        const char* w1p = (const char*)W1T + (size_t)(c * 128 + wn * 32 + l15) * 512 + lk * 16;
        #pragma unroll
        for (int ks = 0; ks < 8; ++ks) {
            int ka = (ks * 64 + lk * 16) ^ swl;
            bf16x8 a0 = *(const bf16x8*)(sE + (r0 + l15) * 512 + ka);
            bf16x8 a1 = *(const bf16x8*)(sE + (r0 + 16 + l15) * 512 + ka);
            bf16x8 b0 = *(const bf16x8*)(w1p + ks * 64);
            bf16x8 b1 = *(const bf16x8*)(w1p + 16 * 512 + ks * 64);
            acc1[0][0] = MFMA(a0, b0, acc1[0][0]);
            acc1[1][0] = MFMA(a1, b0, acc1[1][0]);
            acc1[0][1] = MFMA(a0, b1, acc1[0][1]);
            acc1[1][1] = MFMA(a1, b1, acc1[1][1]);
        }
        float bv0 = b1[c * 128 + wn * 32 + l15];
        float bv1 = b1[c * 128 + wn * 32 + 16 + l15];
        #pragma unroll
        for (int mi = 0; mi < 2; ++mi)
            #pragma unroll
            for (int nj = 0; nj < 2; ++nj) {
                float bv = nj ? bv1 : bv0;
                #pragma unroll
                for (int r = 0; r < 4; ++r) {
                    int row  = r0 + mi * 16 + lk * 4 + r;
                    int coll = wn * 32 + nj * 16 + l15;
                    float v = fmaxf(acc1[mi][nj][r] + bv, 0.f);
                    *(unsigned short*)(sU + row * 256 + ((coll * 2) ^ ((row & 7) << 4))) = f2bf(v);
                }
            }
        __syncthreads();
        // ---- GEMM2 partial: k in [c*128, c*128+128) ----
        const char* w2p = (const char*)W2T + (size_t)(wn * 64 + l15) * 1024 + c * 256 + lk * 16;
        #pragma unroll
        for (int ks = 0; ks < 4; ++ks) {
            int ka = (ks * 64 + lk * 16) ^ swl;
            bf16x8 a0 = *(const bf16x8*)(sU + (r0 + l15) * 256 + ka);
            bf16x8 a1 = *(const bf16x8*)(sU + (r0 + 16 + l15) * 256 + ka);
            #pragma unroll
            for (int nj = 0; nj < 4; ++nj) {
                bf16x8 bb = *(const bf16x8*)(w2p + (size_t)nj * 16 * 1024 + ks * 64);
                acc2[0][nj] = MFMA(a0, bb, acc2[0][nj]);
                acc2[1][nj] = MFMA(a1, bb, acc2[1][nj]);
            }
        }
        __syncthreads();
    }

    // ---- x = e(f32) + f + b2 ; LN stats ----
    float b2v[4], gv[4], btv[4];
    #pragma unroll
    for (int nj = 0; nj < 4; ++nj) {
        int col = wn * 64 + nj * 16 + l15;
        b2v[nj] = b2[col]; gv[nj] = gamma[col]; btv[nj] = beta[col];
    }
    #pragma unroll
    for (int mi = 0; mi < 2; ++mi)
        #pragma unroll
        for (int r = 0; r < 4; ++r) {
            int row = r0 + mi * 16 + lk * 4 + r;
            int vrow = seq[n0 + row];
            float s1 = 0.f, s2 = 0.f;
            #pragma unroll
            for (int nj = 0; nj < 4; ++nj) {
                int col = wn * 64 + nj * 16 + l15;
                float e = embed[(size_t)vrow * 256 + col];   // f32 residual (exact)
                float x = acc2[mi][nj][r] + b2v[nj] + e;
                acc2[mi][nj][r] = x;
                s1 += x; s2 = fmaf(x, x, s2);
            }
            s1 += __shfl_xor(s1, 1); s2 += __shfl_xor(s2, 1);
            s1 += __shfl_xor(s1, 2); s2 += __shfl_xor(s2, 2);
            s1 += __shfl_xor(s1, 4); s2 += __shfl_xor(s2, 4);
            s1 += __shfl_xor(s1, 8); s2 += __shfl_xor(s2, 8);
            if (l15 == 0) { sPart[row][wn][0] = s1; sPart[row][wn][1] = s2; }
        }
    __syncthreads();
    if (tid < 64) {
        float t1 = sPart[tid][0][0] + sPart[tid][1][0] + sPart[tid][2][0] + sPart[tid][3][0];
        float t2 = sPart[tid][0][1] + sPart[tid][1][1] + sPart[tid][2][1] + sPart[tid][3][1];
        float mu  = t1 * (1.f / 256.f);
        float var = t2 * (1.f / 256.f) - mu * mu;
        sMR[tid][0] = mu;
        sMR[tid][1] = rsqrtf(var + 1e-5f);
    }
    __syncthreads();
    // ---- h -> sE (bf16, swizzled) ----
    #pragma unroll
    for (int mi = 0; mi < 2; ++mi)
        #pragma unroll
        for (int r = 0; r < 4; ++r) {
            int row = r0 + mi * 16 + lk * 4 + r;
            int swr = (row & 7) << 4;
            float mu = sMR[row][0], rs = sMR[row][1];
            #pragma unroll
            for (int nj = 0; nj < 4; ++nj) {
                int col = wn * 64 + nj * 16 + l15;
                float h = (acc2[mi][nj][r] - mu) * rs * gv[nj] + btv[nj];
                *(unsigned short*)(sE + row * 512 + ((col * 2) ^ swr)) = f2bf(h);
            }
        }
    __syncthreads();

    // ---- GEMM3: p = h @ WpT^T + bp ----
    f32x4 acc3[2][2];
    acc3[0][0] = acc3[0][1] = acc3[1][0] = acc3[1][1] = (f32x4){0.f, 0.f, 0.f, 0.f};
    const char* wpp = (const char*)WpT + (size_t)(wn * 32 + l15) * 512 + lk * 16;
    #pragma unroll
    for (int ks = 0; ks < 8; ++ks) {
        int ka = (ks * 64 + lk * 16) ^ swl;
        bf16x8 a0 = *(const bf16x8*)(sE + (r0 + l15) * 512 + ka);
        bf16x8 a1 = *(const bf16x8*)(sE + (r0 + 16 + l15) * 512 + ka);
        bf16x8 b0 = *(const bf16x8*)(wpp + ks * 64);
        bf16x8 b1 = *(const bf16x8*)(wpp + 16 * 512 + ks * 64);
        acc3[0][0] = MFMA(a0, b0, acc3[0][0]);
        acc3[1][0] = MFMA(a1, b0, acc3[1][0]);
        acc3[0][1] = MFMA(a0, b1, acc3[0][1]);
        acc3[1][1] = MFMA(a1, b1, acc3[1][1]);
    }
    float bp0 = bp[wn * 32 + l15], bp1 = bp[wn * 32 + 16 + l15];
    #pragma unroll
    for (int mi = 0; mi < 2; ++mi)
        #pragma unroll
        for (int nj = 0; nj < 2; ++nj)
            #pragma unroll
            for (int r = 0; r < 4; ++r) {
                int row = r0 + mi * 16 + lk * 4 + r;
                int col = wn * 32 + nj * 16 + l15;
                *(unsigned short*)(sU + row * 256 + col * 2) =
                    f2bf(acc3[mi][nj][r] + (nj ? bp1 : bp0));
            }
    __syncthreads();
    #pragma unroll
    for (int ii = 0; ii < 2; ++ii) {
        int idx = tid * 2 + ii;            // 0..1023
        int row = idx >> 4, slot = (idx & 15) << 4;
        *(uint4*)((char*)p_bf + (size_t)(n0 + row) * 256 + slot) =
            *(const uint4*)(sU + row * 256 + slot);
    }
}

// ---------------- Gq precompute: {1/(k.k+eps), k_t.k_{t+1..3}} ----------------
__global__ __launch_bounds__(256) void gq_kernel(
    const unsigned short* __restrict__ p_bf, float* __restrict__ Gq)
{
    int b  = blockIdx.x >> 6;
    int t  = ((blockIdx.x & 63) << 5) + (threadIdx.x >> 3);
    int l8 = threadIdx.x & 7;
    const unsigned short* pb = p_bf + (size_t)b * Ll * 128;

    float k0[16];
    {
        uint4 u0 = *(const uint4*)(pb + (size_t)t * 128 + l8 * 16);
        uint4 u1 = *(const uint4*)(pb + (size_t)t * 128 + l8 * 16 + 8);
        unpk8(u0, k0); unpk8(u1, k0 + 8);
    }
    float d0 = 0.f, dg[3];
    #pragma unroll
    for (int i = 0; i < 16; ++i) d0 = fmaf(k0[i], k0[i], d0);
    #pragma unroll
    for (int d = 1; d <= 3; ++d) {
        int tr = t + d; if (tr > 2047) tr = 2047;
        float kd[16];
        uint4 u0 = *(const uint4*)(pb + (size_t)tr * 128 + l8 * 16);
        uint4 u1 = *(const uint4*)(pb + (size_t)tr * 128 + l8 * 16 + 8);
        unpk8(u0, kd); unpk8(u1, kd + 8);
        float a = 0.f;
        #pragma unroll
        for (int i = 0; i < 16; ++i) a = fmaf(k0[i], kd[i], a);
        dg[d - 1] = a;
    }
    d0    += __shfl_xor(d0, 1);    d0    += __shfl_xor(d0, 2);    d0    += __shfl_xor(d0, 4);
    dg[0] += __shfl_xor(dg[0], 1); dg[0] += __shfl_xor(dg[0], 2); dg[0] += __shfl_xor(dg[0], 4);
    dg[1] += __shfl_xor(dg[1], 1); dg[1] += __shfl_xor(dg[1], 2); dg[1] += __shfl_xor(dg[1], 4);
    dg[2] += __shfl_xor(dg[2], 1); dg[2] += __shfl_xor(dg[2], 2); dg[2] += __shfl_xor(dg[2], 4);
    if (l8 == 0) {
        float4 o; o.x = 1.f / (d0 + 1e-6f); o.y = dg[0]; o.z = dg[1]; o.w = dg[2];
        *(float4*)(Gq + ((size_t)b * Ll + t) * 4) = o;
    }
}

// ---------------- backward vector scan: cs = sum_t (k_t . u_t) k_t ----------------
__global__ __launch_bounds__(64) void scan_kernel(
    const unsigned short* __restrict__ p_bf, const float* __restrict__ Gq,
    float* __restrict__ csb)
{
    __shared__ unsigned short kbuf[2][64 * 128];
    __shared__ float gqbuf[2][64 * 4];
    const int b    = blockIdx.x;
    const int lane = threadIdx.x;
    const int l32  = lane & 31;
    const unsigned short* pb  = p_bf + (size_t)b * Ll * 128;
    const float*          gqb = Gq + (size_t)b * Ll * 4;

    f32x4 u   = cvt4(*(const ushort4*)(pb + 2047 * 128 + l32 * 4));
    f32x4 csv = (f32x4){0.f, 0.f, 0.f, 0.f};

    // head: 3 single steps (t = 2046..2044), 2044 remaining = 511 groups of 4
    for (int tt = 2046; tt >= 2044; --tt) {
        f32x4 k = cvt4(*(const ushort4*)(pb + (size_t)tt * 128 + l32 * 4));
        float c = k.x * u.x + k.y * u.y + k.z * u.z + k.w * u.w;
        c += __shfl_xor(c, 1); c += __shfl_xor(c, 2); c += __shfl_xor(c, 4);
        c += __shfl_xor(c, 8); c += __shfl_xor(c, 16);
        float z = c * gqb[tt * 4];
        u.x = fmaf(-z, k.x, u.x); u.y = fmaf(-z, k.y, u.y);
        u.z = fmaf(-z, k.z, u.z); u.w = fmaf(-z, k.w, u.w);
        csv.x = fmaf(c, k.x, csv.x); csv.y = fmaf(c, k.y, csv.y);
        csv.z = fmaf(c, k.z, csv.z); csv.w = fmaf(c, k.w, csv.w);
    }

    auto STAGE = [&](int s, int tTop) {          // 17 global_load_lds per call
        #pragma unroll
        for (int j = 0; j < 16; ++j) {
            int i = j * 4 + (lane >> 4);
            int tt = tTop - i; tt = tt < 0 ? 0 : tt;
            const char* src = (const char*)pb + (size_t)tt * 256 + (lane & 15) * 16;
            GLL16(src, (char*)kbuf[s] + j * 1024);
        }
        int tg = tTop - lane; tg = tg < 0 ? 0 : tg;
        GLL16((const char*)gqb + (size_t)tg * 16, (char*)gqbuf[s]);
    };

    STAGE(0, 2043);
    STAGE(1, 2043 - 64);
    #pragma unroll 1
    for (int j = 0; j < 32; ++j) {
        const int cur = j & 1;
        if (j < 31) { asm volatile("s_waitcnt vmcnt(17)" ::: "memory"); }
        else        { asm volatile("s_waitcnt vmcnt(0)"  ::: "memory"); }
        const unsigned short* kb = kbuf[cur];
        const float*          gq = gqbuf[cur];
        const int ng = (j < 31) ? 16 : 15;
        #pragma unroll 4
        for (int g = 0; g < ng; ++g) {
            int i0 = g * 4;
            f32x4 k0 = cvt4(*(const ushort4*)(kb + (i0 + 0) * 128 + l32 * 4));
            f32x4 k1 = cvt4(*(const ushort4*)(kb + (i0 + 1) * 128 + l32 * 4));
            f32x4 k2 = cvt4(*(const ushort4*)(kb + (i0 + 2) * 128 + l32 * 4));
            f32x4 k3 = cvt4(*(const ushort4*)(kb + (i0 + 3) * 128 + l32 * 4));
            f32x4 q0 = *(const f32x4*)(gq + (i0 + 0) * 4);
            f32x4 q1 = *(const f32x4*)(gq + (i0 + 1) * 4);
            f32x4 q2 = *(const f32x4*)(gq + (i0 + 2) * 4);
            f32x4 q3 = *(const f32x4*)(gq + (i0 + 3) * 4);
            float c0 = k0.x * u.x + k0.y * u.y + k0.z * u.z + k0.w * u.w;
            float c1 = k1.x * u.x + k1.y * u.y + k1.z * u.z + k1.w * u.w;
            float c2 = k2.x * u.x + k2.y * u.y + k2.z * u.z + k2.w * u.w;
            float c3 = k3.x * u.x + k3.y * u.y + k3.z * u.z + k3.w * u.w;
            c0 += __shfl_xor(c0, 1); c1 += __shfl_xor(c1, 1); c2 += __shfl_xor(c2, 1); c3 += __shfl_xor(c3, 1);
            c0 += __shfl_xor(c0, 2); c1 += __shfl_xor(c1, 2); c2 += __shfl_xor(c2, 2); c3 += __shfl_xor(c3, 2);
            c0 += __shfl_xor(c0, 4); c1 += __shfl_xor(c1, 4); c2 += __shfl_xor(c2, 4); c3 += __shfl_xor(c3, 4);
            c0 += __shfl_xor(c0, 8); c1 += __shfl_xor(c1, 8); c2 += __shfl_xor(c2, 8); c3 += __shfl_xor(c3, 8);
            c0 += __shfl_xor(c0, 16); c1 += __shfl_xor(c1, 16); c2 += __shfl_xor(c2, 16); c3 += __shfl_xor(c3, 16);
            // triangular solve (descending t: t0, t0-1, t0-2, t0-3)
            float z0 = c0 * q0.x;
            float y1 = fmaf(-z0, q1.y, c1);
            float z1 = y1 * q1.x;
            float y2 = fmaf(-z1, q2.y, fmaf(-z0, q2.z, c2));
            float z2 = y2 * q2.x;
            float y3 = fmaf(-z2, q3.y, fmaf(-z1, q3.z, fmaf(-z0, q3.w, c3)));
            float z3 = y3 * q3.x;
            u.x = fmaf(-z3, k3.x, fmaf(-z2, k2.x, fmaf(-z1, k1.x, fmaf(-z0, k0.x, u.x))));
            u.y = fmaf(-z3, k3.y, fmaf(-z2, k2.y, fmaf(-z1, k1.y, fmaf(-z0, k0.y, u.y))));
            u.z = fmaf(-z3, k3.z, fmaf(-z2, k2.z, fmaf(-z1, k1.z, fmaf(-z0, k0.z, u.z))));
            u.w = fmaf(-z3, k3.w, fmaf(-z2, k2.w, fmaf(-z1, k1.w, fmaf(-z0, k0.w, u.w))));
            csv.x = fmaf(y3, k3.x, fmaf(y2, k2.x, fmaf(y1, k1.x, fmaf(c0, k0.x, csv.x))));
            csv.y = fmaf(y3, k3.y, fmaf(y2, k2.y, fmaf(y1, k1.y, fmaf(c0, k0.y, csv.y))));
            csv.z = fmaf(y3, k3.z, fmaf(y2, k2.z, fmaf(y1, k1.z, fmaf(c0, k0.z, csv.z))));
            csv.w = fmaf(y3, k3.w, fmaf(y2, k2.w, fmaf(y1, k1.w, fmaf(c0, k0.w, csv.w))));
        }
        asm volatile("s_waitcnt lgkmcnt(0)" ::: "memory");
        if (j + 2 < 32) STAGE(cur, 2043 - 64 * (j + 2));
    }
    if (lane < 32) *(f32x4*)(csb + b * 128 + lane * 4) = csv;
}

// ---------------- out = cs @ Wo + bo : [64,128]@[128,32000] ----------------
__global__ __launch_bounds__(256) void out_kernel(
    const float* __restrict__ cs, const float* __restrict__ Wo,
    const float* __restrict__ bo, float* __restrict__ out)
{
    __shared__ float sC[64 * 128];
    const int tid = threadIdx.x;
    #pragma unroll
    for (int r = 0; r < 8; ++r)
        ((float4*)sC)[r * 256 + tid] = ((const float4*)cs)[r * 256 + tid];
    __syncthreads();

    const int j = blockIdx.x * 256 + tid;
    float acc[64];
    #pragma unroll
    for (int r = 0; r < 64; ++r) acc[r] = 0.f;
    for (int k0 = 0; k0 < 128; k0 += 4) {
        float w0 = Wo[(size_t)(k0 + 0) * Vv + j];
        float w1 = Wo[(size_t)(k0 + 1) * Vv + j];
        float w2 = Wo[(size_t)(k0 + 2) * Vv + j];
        float w3 = Wo[(size_t)(k0 + 3) * Vv + j];
        #pragma unroll
        for (int r = 0; r < 64; ++r) {
            float4 c = *(const float4*)&sC[r * 128 + k0];
            acc[r] = fmaf(c.x, w0, fmaf(c.y, w1, fmaf(c.z, w2, fmaf(c.w, w3, acc[r]))));
        }
    }
    float bj = bo[j];
    #pragma unroll
    for (int r = 0; r < 64; ++r)
        out[(size_t)r * Vv + j] = acc[r] + bj;
}

extern "C" void kernel_launch(void* const* d_in, const int* in_sizes, int n_in,
                              void* d_out, int out_size, void* d_ws, size_t ws_size,
                              hipStream_t stream)
{
    const int*   seq   = (const int*)  d_in[0];
    const float* embed = (const float*)d_in[1];
    const float* W1    = (const float*)d_in[2];
    const float* b1    = (const float*)d_in[3];
    const float* W2    = (const float*)d_in[4];
    const float* b2    = (const float*)d_in[5];
    const float* gamma = (const float*)d_in[6];
    const float* beta  = (const float*)d_in[7];
    const float* Wp    = (const float*)d_in[8];
    const float* bp    = (const float*)d_in[9];
    const float* Wo    = (const float*)d_in[10];
    const float* bo    = (const float*)d_in[11];
    float* out = (float*)d_out;

    char* wsb = (char*)d_ws;
    unsigned short* p_bf = (unsigned short*)(wsb);                 // 33,554,432 B
    float*          Gq   = (float*)(wsb + 33554432);               //  2,097,152 B
    unsigned short* W1T  = (unsigned short*)(wsb + 35651584);      //    262,144 B
    unsigned short* W2T  = (unsigned short*)(wsb + 35913728);      //    262,144 B
    unsigned short* WpT  = (unsigned short*)(wsb + 36175872);      //     65,536 B
    float*          csb  = (float*)(wsb + 36241408);               //     32,768 B

    prep_kernel<<<576, 256, 0, stream>>>(W1, W2, Wp, W1T, W2T, WpT);
    enc_kernel<<<2048, 512, 0, stream>>>(seq, embed, W1T, b1, W2T, b2,
                                         gamma, beta, WpT, bp, p_bf);
    gq_kernel<<<4096, 256, 0, stream>>>(p_bf, Gq);
    scan_kernel<<<64, 64, 0, stream>>>(p_bf, Gq, csb);
    out_kernel<<<Vv / 256, 256, 0, stream>>>(csb, Wo, bo, out);
}

// Round 3
// 371.357 us; speedup vs baseline: 8.4292x; 1.6436x over previous
//
#include <hip/hip_runtime.h>

#define Vv 32000
#define Ll 2048

typedef __bf16 bf16x8 __attribute__((ext_vector_type(8)));
typedef float  f32x4  __attribute__((ext_vector_type(4)));

__device__ __forceinline__ unsigned short f2bf(float f) {
    unsigned u = __builtin_bit_cast(unsigned, f);
    u += 0x7fffu + ((u >> 16) & 1u);
    return (unsigned short)(u >> 16);
}
__device__ __forceinline__ float bf2f(unsigned short s) {
    unsigned u = (unsigned)s << 16;
    return __builtin_bit_cast(float, u);
}
__device__ __forceinline__ void unpk8(uint4 v, float* o) {
    o[0] = bf2f((unsigned short)(v.x & 0xffff)); o[1] = bf2f((unsigned short)(v.x >> 16));
    o[2] = bf2f((unsigned short)(v.y & 0xffff)); o[3] = bf2f((unsigned short)(v.y >> 16));
    o[4] = bf2f((unsigned short)(v.z & 0xffff)); o[5] = bf2f((unsigned short)(v.z >> 16));
    o[6] = bf2f((unsigned short)(v.w & 0xffff)); o[7] = bf2f((unsigned short)(v.w >> 16));
}

#define MFMA(a, b, c) __builtin_amdgcn_mfma_f32_16x16x32_bf16(a, b, c, 0, 0, 0)
#define GLL16(gsrc, ldst)                                                    \
    __builtin_amdgcn_global_load_lds(                                        \
        (const __attribute__((address_space(1))) void*)(gsrc),               \
        (__attribute__((address_space(3))) void*)(ldst), 16, 0, 0)
#define GLL4(gsrc, ldst)                                                     \
    __builtin_amdgcn_global_load_lds(                                        \
        (const __attribute__((address_space(1))) void*)(gsrc),               \
        (__attribute__((address_space(3))) void*)(ldst), 4, 0, 0)

// ---------------- prep: transpose W1/W2/Wp to bf16 [N][K]; zero pad row ----
__global__ __launch_bounds__(256) void prep_kernel(
    const float* __restrict__ W1, const float* __restrict__ W2,
    const float* __restrict__ Wp, unsigned short* __restrict__ W1T,
    unsigned short* __restrict__ W2T, unsigned short* __restrict__ WpT,
    float* __restrict__ zrow)
{
    int idx = blockIdx.x * 256 + threadIdx.x;   // pair index
    if (blockIdx.x == 575 && threadIdx.x < 64) zrow[threadIdx.x] = 0.f;
    if (idx < 65536) {                           // W1T [512][256] <- W1 [256][512]
        int e0 = idx * 2, n = e0 >> 8, k = e0 & 255;
        unsigned lo = f2bf(W1[(size_t)k * 512 + n]);
        unsigned hi = f2bf(W1[(size_t)(k + 1) * 512 + n]);
        ((unsigned*)W1T)[idx] = lo | (hi << 16);
    } else if (idx < 131072) {                   // W2T [256][512] <- W2 [512][256]
        int i = idx - 65536, e0 = i * 2, n = e0 >> 9, k = e0 & 511;
        unsigned lo = f2bf(W2[(size_t)k * 256 + n]);
        unsigned hi = f2bf(W2[(size_t)(k + 1) * 256 + n]);
        ((unsigned*)W2T)[i] = lo | (hi << 16);
    } else {                                     // WpT [128][256] <- Wp [256][128]
        int i = idx - 131072, e0 = i * 2, n = e0 >> 8, k = e0 & 255;
        unsigned lo = f2bf(Wp[(size_t)k * 128 + n]);
        unsigned hi = f2bf(Wp[(size_t)(k + 1) * 128 + n]);
        ((unsigned*)WpT)[i] = lo | (hi << 16);
    }
}

// ---------------- fused MFMA encoder over the VOCABULARY (32000 rows) ------
// 512 threads = 8 waves (2 M-groups x 4 N-groups), 64 vocab rows per block.
__global__ __launch_bounds__(512, 4) void enc_kernel(
    const float* __restrict__ embed,
    const unsigned short* __restrict__ W1T, const float* __restrict__ b1,
    const unsigned short* __restrict__ W2T, const float* __restrict__ b2,
    const float* __restrict__ gamma, const float* __restrict__ beta,
    const unsigned short* __restrict__ WpT, const float* __restrict__ bp,
    unsigned short* __restrict__ ptab)
{
    __shared__ char sE[64 * 512];      // bf16 [64][256], XOR-swizzled (e, then h)
    __shared__ char sU[64 * 256];      // bf16 [64][128], swizzled (U chunk) / plain (p stage)
    __shared__ float sPart[64][4][2];
    __shared__ float sMR[64][2];

    const int tid  = threadIdx.x;
    const int lane = tid & 63;
    const int w    = tid >> 6;
    const int wm   = w >> 2;           // 0..1
    const int wn   = w & 3;            // 0..3
    const int l15  = lane & 15;
    const int lk   = lane >> 4;        // 0..3
    const int n0   = blockIdx.x * 64;
    const int r0   = wm * 32;
    const int swl  = (l15 & 7) << 4;   // A-frag row swizzle (row&7 == l15&7)

    // ---- load E tile: identity rows (coalesced), f32 -> bf16 swizzled ----
    #pragma unroll
    for (int cc = 0; cc < 4; ++cc) {
        int c = cc * 512 + tid;          // 0..2047 16B-chunks
        int row  = c >> 5;
        int slot = (c & 31) << 4;
        int kbs  = slot ^ ((row & 7) << 4);
        const float* src = embed + (size_t)(n0 + row) * 256 + (kbs >> 1);
        float4 a = *(const float4*)src;
        float4 b = *(const float4*)(src + 4);
        uint4 pk;
        pk.x = (unsigned)f2bf(a.x) | ((unsigned)f2bf(a.y) << 16);
        pk.y = (unsigned)f2bf(a.z) | ((unsigned)f2bf(a.w) << 16);
        pk.z = (unsigned)f2bf(b.x) | ((unsigned)f2bf(b.y) << 16);
        pk.w = (unsigned)f2bf(b.z) | ((unsigned)f2bf(b.w) << 16);
        *(uint4*)(sE + row * 512 + slot) = pk;
    }
    __syncthreads();

    f32x4 acc2[2][4];
    #pragma unroll
    for (int i = 0; i < 2; ++i)
        #pragma unroll
        for (int j = 0; j < 4; ++j) acc2[i][j] = (f32x4){0.f, 0.f, 0.f, 0.f};

    #pragma unroll 1
    for (int c = 0; c < 4; ++c) {
        // ---- GEMM1 chunk: cols [c*128, c*128+128) ----
        f32x4 acc1[2][2];
        acc1[0][0] = acc1[0][1] = acc1[1][0] = acc1[1][1] = (f32x4){0.f, 0.f, 0.f, 0.f};
        const char* w1p = (const char*)W1T + (size_t)(c * 128 + wn * 32 + l15) * 512 + lk * 16;
        #pragma unroll
        for (int ks = 0; ks < 8; ++ks) {
            int ka = (ks * 64 + lk * 16) ^ swl;
            bf16x8 a0 = *(const bf16x8*)(sE + (r0 + l15) * 512 + ka);
            bf16x8 a1 = *(const bf16x8*)(sE + (r0 + 16 + l15) * 512 + ka);
            bf16x8 b0 = *(const bf16x8*)(w1p + ks * 64);
            bf16x8 b1 = *(const bf16x8*)(w1p + 16 * 512 + ks * 64);
            acc1[0][0] = MFMA(a0, b0, acc1[0][0]);
            acc1[1][0] = MFMA(a1, b0, acc1[1][0]);
            acc1[0][1] = MFMA(a0, b1, acc1[0][1]);
            acc1[1][1] = MFMA(a1, b1, acc1[1][1]);
        }
        float bv0 = b1[c * 128 + wn * 32 + l15];
        float bv1 = b1[c * 128 + wn * 32 + 16 + l15];
        #pragma unroll
        for (int mi = 0; mi < 2; ++mi)
            #pragma unroll
            for (int nj = 0; nj < 2; ++nj) {
                float bv = nj ? bv1 : bv0;
                #pragma unroll
                for (int r = 0; r < 4; ++r) {
                    int row  = r0 + mi * 16 + lk * 4 + r;
                    int coll = wn * 32 + nj * 16 + l15;
                    float v = fmaxf(acc1[mi][nj][r] + bv, 0.f);
                    *(unsigned short*)(sU + row * 256 + ((coll * 2) ^ ((row & 7) << 4))) = f2bf(v);
                }
            }
        __syncthreads();
        // ---- GEMM2 partial: k in [c*128, c*128+128) ----
        const char* w2p = (const char*)W2T + (size_t)(wn * 64 + l15) * 1024 + c * 256 + lk * 16;
        #pragma unroll
        for (int ks = 0; ks < 4; ++ks) {
            int ka = (ks * 64 + lk * 16) ^ swl;
            bf16x8 a0 = *(const bf16x8*)(sU + (r0 + l15) * 256 + ka);
            bf16x8 a1 = *(const bf16x8*)(sU + (r0 + 16 + l15) * 256 + ka);
            #pragma unroll
            for (int nj = 0; nj < 4; ++nj) {
                bf16x8 bb = *(const bf16x8*)(w2p + (size_t)nj * 16 * 1024 + ks * 64);
                acc2[0][nj] = MFMA(a0, bb, acc2[0][nj]);
                acc2[1][nj] = MFMA(a1, bb, acc2[1][nj]);
            }
        }
        __syncthreads();
    }

    // ---- x = e(bf16 from LDS) + f + b2 ; LN stats ----
    float b2v[4], gv[4], btv[4];
    #pragma unroll
    for (int nj = 0; nj < 4; ++nj) {
        int col = wn * 64 + nj * 16 + l15;
        b2v[nj] = b2[col]; gv[nj] = gamma[col]; btv[nj] = beta[col];
    }
    #pragma unroll
    for (int mi = 0; mi < 2; ++mi)
        #pragma unroll
        for (int r = 0; r < 4; ++r) {
            int row = r0 + mi * 16 + lk * 4 + r;
            int swr = (row & 7) << 4;
            float s1 = 0.f, s2 = 0.f;
            #pragma unroll
            for (int nj = 0; nj < 4; ++nj) {
                int col = wn * 64 + nj * 16 + l15;
                float e = bf2f(*(const unsigned short*)(sE + row * 512 + ((col * 2) ^ swr)));
                float x = acc2[mi][nj][r] + b2v[nj] + e;
                acc2[mi][nj][r] = x;
                s1 += x; s2 = fmaf(x, x, s2);
            }
            s1 += __shfl_xor(s1, 1); s2 += __shfl_xor(s2, 1);
            s1 += __shfl_xor(s1, 2); s2 += __shfl_xor(s2, 2);
            s1 += __shfl_xor(s1, 4); s2 += __shfl_xor(s2, 4);
            s1 += __shfl_xor(s1, 8); s2 += __shfl_xor(s2, 8);
            if (l15 == 0) { sPart[row][wn][0] = s1; sPart[row][wn][1] = s2; }
        }
    __syncthreads();
    if (tid < 64) {
        float t1 = sPart[tid][0][0] + sPart[tid][1][0] + sPart[tid][2][0] + sPart[tid][3][0];
        float t2 = sPart[tid][0][1] + sPart[tid][1][1] + sPart[tid][2][1] + sPart[tid][3][1];
        float mu  = t1 * (1.f / 256.f);
        float var = t2 * (1.f / 256.f) - mu * mu;
        sMR[tid][0] = mu;
        sMR[tid][1] = rsqrtf(var + 1e-5f);
    }
    __syncthreads();
    // ---- h -> sE (bf16, swizzled) ----
    #pragma unroll
    for (int mi = 0; mi < 2; ++mi)
        #pragma unroll
        for (int r = 0; r < 4; ++r) {
            int row = r0 + mi * 16 + lk * 4 + r;
            int swr = (row & 7) << 4;
            float mu = sMR[row][0], rs = sMR[row][1];
            #pragma unroll
            for (int nj = 0; nj < 4; ++nj) {
                int col = wn * 64 + nj * 16 + l15;
                float h = (acc2[mi][nj][r] - mu) * rs * gv[nj] + btv[nj];
                *(unsigned short*)(sE + row * 512 + ((col * 2) ^ swr)) = f2bf(h);
            }
        }
    __syncthreads();

    // ---- GEMM3: p = h @ WpT^T + bp ----
    f32x4 acc3[2][2];
    acc3[0][0] = acc3[0][1] = acc3[1][0] = acc3[1][1] = (f32x4){0.f, 0.f, 0.f, 0.f};
    const char* wpp = (const char*)WpT + (size_t)(wn * 32 + l15) * 512 + lk * 16;
    #pragma unroll
    for (int ks = 0; ks < 8; ++ks) {
        int ka = (ks * 64 + lk * 16) ^ swl;
        bf16x8 a0 = *(const bf16x8*)(sE + (r0 + l15) * 512 + ka);
        bf16x8 a1 = *(const bf16x8*)(sE + (r0 + 16 + l15) * 512 + ka);
        bf16x8 b0 = *(const bf16x8*)(wpp + ks * 64);
        bf16x8 b1 = *(const bf16x8*)(wpp + 16 * 512 + ks * 64);
        acc3[0][0] = MFMA(a0, b0, acc3[0][0]);
        acc3[1][0] = MFMA(a1, b0, acc3[1][0]);
        acc3[0][1] = MFMA(a0, b1, acc3[0][1]);
        acc3[1][1] = MFMA(a1, b1, acc3[1][1]);
    }
    float bp0 = bp[wn * 32 + l15], bp1 = bp[wn * 32 + 16 + l15];
    #pragma unroll
    for (int mi = 0; mi < 2; ++mi)
        #pragma unroll
        for (int nj = 0; nj < 2; ++nj)
            #pragma unroll
            for (int r = 0; r < 4; ++r) {
                int row = r0 + mi * 16 + lk * 4 + r;
                int col = wn * 32 + nj * 16 + l15;
                *(unsigned short*)(sU + row * 256 + col * 2) =
                    f2bf(acc3[mi][nj][r] + (nj ? bp1 : bp0));
            }
    __syncthreads();
    #pragma unroll
    for (int ii = 0; ii < 2; ++ii) {
        int idx = tid * 2 + ii;            // 0..1023
        int row = idx >> 4, slot = (idx & 15) << 4;
        *(uint4*)((char*)ptab + (size_t)(n0 + row) * 256 + slot) =
            *(const uint4*)(sU + row * 256 + slot);
    }
}

// ---------------- sprep: per-chunk Gram (MFMA) + S = (D+L)^-1 (subst) ------
// One 64-thread block per (batch, chunk). Chunk ch: row i <-> t = 2047-64*ch-i.
__global__ __launch_bounds__(64) void sprep_kernel(
    const int* __restrict__ seq, const unsigned short* __restrict__ ptab,
    float* __restrict__ STg, float* __restrict__ qvec)
{
    __shared__ unsigned short sK[64 * 136];   // rows padded to 272 B
    __shared__ float sG[64 * 68];             // rows 272 B
    __shared__ float sST[64 * 66];            // rows 264 B (ST[j][i] = S[i][j])

    const int blk = blockIdx.x;               // 0..2047
    const int b = blk >> 5, ch = blk & 31;
    const int t_hi = 2047 - (ch << 6);
    const int lane = threadIdx.x;

    // ---- gather K rows (lane = row i); zero the query-pad row ----
    {
        int t = t_hi - lane;
        if (t == 2047) {
            #pragma unroll
            for (int j = 0; j < 16; ++j)
                *(uint4*)((char*)sK + lane * 272 + j * 16) = (uint4){0u, 0u, 0u, 0u};
        } else {
            int v = seq[b * 2048 + t];
            const char* src = (const char*)(ptab + (size_t)v * 128);
            #pragma unroll
            for (int j = 0; j < 16; ++j)
                *(uint4*)((char*)sK + lane * 272 + j * 16) = *(const uint4*)(src + j * 16);
        }
    }
    __syncthreads();

    // ---- Gram: lower tiles (ti >= tj), 16x16x32 MFMA over K=128 ----
    const int l15 = lane & 15, lk = lane >> 4;
    f32x4 acc[10];
    #pragma unroll
    for (int q = 0; q < 10; ++q) acc[q] = (f32x4){0.f, 0.f, 0.f, 0.f};
    #pragma unroll
    for (int ks = 0; ks < 4; ++ks) {
        bf16x8 fr[4];
        #pragma unroll
        for (int t4 = 0; t4 < 4; ++t4)
            fr[t4] = *(const bf16x8*)((const char*)sK + (t4 * 16 + l15) * 272 + ks * 64 + lk * 16);
        int q = 0;
        #pragma unroll
        for (int ti = 0; ti < 4; ++ti)
            #pragma unroll
            for (int tj = 0; tj <= ti; ++tj, ++q)
                acc[q] = MFMA(fr[ti], fr[tj], acc[q]);
    }
    {
        int q = 0;
        #pragma unroll
        for (int ti = 0; ti < 4; ++ti)
            #pragma unroll
            for (int tj = 0; tj <= ti; ++tj, ++q)
                #pragma unroll
                for (int r = 0; r < 4; ++r)
                    sG[(ti * 16 + lk * 4 + r) * 68 + tj * 16 + l15] = acc[q][r];
    }
    __syncthreads();

    // ---- forward substitution: column j per lane; ST[j][i] = S[i][j] ----
    {
        float qi0 = 1.f / (sG[0] + 1e-6f);
        sST[lane * 66 + 0] = (lane == 0) ? qi0 : 0.f;
    }
    for (int i = 1; i < 64; ++i) {
        float sum = 0.f;
        const float* strow = &sST[lane * 66];
        int m = 0;
        for (; m + 2 <= i; m += 2) {
            float2 sv = *(const float2*)&strow[m];
            float2 gv = *(const float2*)&sG[i * 68 + m];
            sum = fmaf(sv.x, gv.x, sum);
            sum = fmaf(sv.y, gv.y, sum);
        }
        if (m < i) sum = fmaf(strow[m], sG[i * 68 + m], sum);
        float qi = 1.f / (sG[i * 68 + i] + 1e-6f);
        sST[lane * 66 + i] = (((lane == i) ? 1.f : 0.f) - sum) * qi;
    }
    __syncthreads();

    // ---- write ST [64][64] f32 and qvec ----
    float* stg = STg + ((size_t)blk << 12);
    #pragma unroll
    for (int rr = 0; rr < 32; ++rr) {
        int r  = rr * 2 + (lane >> 5);
        int i2 = (lane & 31) * 2;
        float2 v = *(const float2*)&sST[r * 66 + i2];
        *(float2*)(stg + r * 64 + i2) = v;
    }
    qvec[(blk << 6) + lane] = sG[lane * 68 + lane] + 1e-6f;
}

// ---------------- serial chunked scan: 1 wave per batch ----------------
__global__ __launch_bounds__(64) void scan_kernel(
    const int* __restrict__ seq, const unsigned short* __restrict__ ptab,
    const float* __restrict__ STg, const float* __restrict__ qvec,
    const float* __restrict__ zrow, float* __restrict__ csb)
{
    __shared__ int sSeq[2048];
    __shared__ unsigned short sKb[2][8192];   // [64][128] bf16, linear
    __shared__ float sSTb[2][4096];           // [j][i]
    __shared__ float sQb[2][64];
    __shared__ float sU[128];
    __shared__ float sB[64];
    __shared__ float sZC[128];                // (z_i, c_i)

    const int b = blockIdx.x;
    const int lane = threadIdx.x;

    #pragma unroll
    for (int r = 0; r < 8; ++r)
        *(int4*)&sSeq[r * 256 + lane * 4] = *(const int4*)&seq[b * 2048 + r * 256 + lane * 4];
    {
        int vq = seq[b * 2048 + 2047];
        unsigned pk = *(const unsigned*)(ptab + (size_t)vq * 128 + lane * 2);
        sU[lane * 2]     = bf2f((unsigned short)(pk & 0xffff));
        sU[lane * 2 + 1] = bf2f((unsigned short)(pk >> 16));
    }
    float csv0 = 0.f, csv1 = 0.f;
    __syncthreads();

    auto STAGE = [&](int s, int ch) {
        int t_hi = 2047 - (ch << 6);
        #pragma unroll
        for (int k = 0; k < 16; ++k) {
            int g = k * 64 + lane;
            int r = g >> 4, sd = g & 15;
            int t = t_hi - r;
            int v = sSeq[t];
            const char* srow = (t == 2047) ? (const char*)zrow
                                           : (const char*)(ptab + (size_t)v * 128);
            GLL16(srow + sd * 16, (char*)sKb[s] + k * 1024);
        }
        const char* stsrc = (const char*)(STg + (((size_t)b * 32 + ch) << 12));
        #pragma unroll
        for (int k = 0; k < 16; ++k)
            GLL16(stsrc + k * 1024 + lane * 16, (char*)sSTb[s] + k * 1024);
        GLL4((const char*)(qvec + (((size_t)b * 32 + ch) << 6)) + lane * 4, (char*)sQb[s]);
    };

    STAGE(0, 0); STAGE(1, 1);

    #pragma unroll 1
    for (int c = 0; c < 32; ++c) {
        const int cur = c & 1;
        if (c < 31) { asm volatile("s_waitcnt vmcnt(33)" ::: "memory"); }
        else        { asm volatile("s_waitcnt vmcnt(0)"  ::: "memory"); }
        __builtin_amdgcn_sched_barrier(0);

        const unsigned short* kb = sKb[cur];
        const float* stb = sSTb[cur];

        // phase A: b_i = k_i . u  (lane = i; XOR chunk order for banks)
        float acc = 0.f;
        const int swl = lane & 15;
        #pragma unroll
        for (int ss = 0; ss < 16; ++ss) {
            int jj = ss ^ swl;
            uint4 kv = *(const uint4*)((const char*)kb + lane * 256 + jj * 16);
            f32x4 ua = *(const f32x4*)&sU[jj * 8];
            f32x4 ub = *(const f32x4*)&sU[jj * 8 + 4];
            float kf[8]; unpk8(kv, kf);
            acc = fmaf(kf[0], ua.x, acc); acc = fmaf(kf[1], ua.y, acc);
            acc = fmaf(kf[2], ua.z, acc); acc = fmaf(kf[3], ua.w, acc);
            acc = fmaf(kf[4], ub.x, acc); acc = fmaf(kf[5], ub.y, acc);
            acc = fmaf(kf[6], ub.z, acc); acc = fmaf(kf[7], ub.w, acc);
        }
        sB[lane] = acc;
        __syncthreads();

        // phase B: z_i = sum_j S[i][j] b_j = sum_j ST[j][i] b_j; c_i = q_i z_i
        float z = 0.f;
        #pragma unroll
        for (int j = 0; j < 64; j += 4) {
            f32x4 bj = *(const f32x4*)&sB[j];
            z = fmaf(stb[(j + 0) * 64 + lane], bj.x, z);
            z = fmaf(stb[(j + 1) * 64 + lane], bj.y, z);
            z = fmaf(stb[(j + 2) * 64 + lane], bj.z, z);
            z = fmaf(stb[(j + 3) * 64 + lane], bj.w, z);
        }
        float ci = z * sQb[cur][lane];
        sZC[lane * 2] = z; sZC[lane * 2 + 1] = ci;
        __syncthreads();

        // phase C: u -= K^T z ; cs += K^T c   (lane owns d = 2*lane, 2*lane+1)
        float u0 = sU[lane * 2], u1 = sU[lane * 2 + 1];
        #pragma unroll 4
        for (int i = 0; i < 64; ++i) {
            unsigned kp = *(const unsigned*)((const char*)kb + i * 256 + lane * 4);
            float2 zc = *(const float2*)&sZC[i * 2];
            float k0 = bf2f((unsigned short)(kp & 0xffff));
            float k1 = bf2f((unsigned short)(kp >> 16));
            u0 = fmaf(-zc.x, k0, u0); u1 = fmaf(-zc.x, k1, u1);
            csv0 = fmaf(zc.y, k0, csv0); csv1 = fmaf(zc.y, k1, csv1);
        }
        sU[lane * 2] = u0; sU[lane * 2 + 1] = u1;

        if (c + 2 < 32) STAGE(cur, c + 2);
        __syncthreads();
    }
    csb[b * 128 + lane * 2]     = csv0;
    csb[b * 128 + lane * 2 + 1] = csv1;
}

// ---------------- out = cs @ Wo + bo : [64,128]@[128,32000] ----------------
__global__ __launch_bounds__(256) void out_kernel(
    const float* __restrict__ cs, const float* __restrict__ Wo,
    const float* __restrict__ bo, float* __restrict__ out)
{
    __shared__ float sC[64 * 128];
    const int tid = threadIdx.x;
    #pragma unroll
    for (int r = 0; r < 8; ++r)
        ((float4*)sC)[r * 256 + tid] = ((const float4*)cs)[r * 256 + tid];
    __syncthreads();

    const int j = blockIdx.x * 256 + tid;
    float acc[64];
    #pragma unroll
    for (int r = 0; r < 64; ++r) acc[r] = 0.f;
    for (int k0 = 0; k0 < 128; k0 += 4) {
        float w0 = Wo[(size_t)(k0 + 0) * Vv + j];
        float w1 = Wo[(size_t)(k0 + 1) * Vv + j];
        float w2 = Wo[(size_t)(k0 + 2) * Vv + j];
        float w3 = Wo[(size_t)(k0 + 3) * Vv + j];
        #pragma unroll
        for (int r = 0; r < 64; ++r) {
            float4 c = *(const float4*)&sC[r * 128 + k0];
            acc[r] = fmaf(c.x, w0, fmaf(c.y, w1, fmaf(c.z, w2, fmaf(c.w, w3, acc[r]))));
        }
    }
    float bj = bo[j];
    #pragma unroll
    for (int r = 0; r < 64; ++r)
        out[(size_t)r * Vv + j] = acc[r] + bj;
}

extern "C" void kernel_launch(void* const* d_in, const int* in_sizes, int n_in,
                              void* d_out, int out_size, void* d_ws, size_t ws_size,
                              hipStream_t stream)
{
    const int*   seq   = (const int*)  d_in[0];
    const float* embed = (const float*)d_in[1];
    const float* W1    = (const float*)d_in[2];
    const float* b1    = (const float*)d_in[3];
    const float* W2    = (const float*)d_in[4];
    const float* b2    = (const float*)d_in[5];
    const float* gamma = (const float*)d_in[6];
    const float* beta  = (const float*)d_in[7];
    const float* Wp    = (const float*)d_in[8];
    const float* bp    = (const float*)d_in[9];
    const float* Wo    = (const float*)d_in[10];
    const float* bo    = (const float*)d_in[11];
    float* out = (float*)d_out;

    char* wsb = (char*)d_ws;
    unsigned short* ptab = (unsigned short*)(wsb);                 //  8,192,000 B
    float*          STg  = (float*)(wsb + 8192000);                // 33,554,432 B
    float*          qvec = (float*)(wsb + 41746432);               //    524,288 B
    unsigned short* W1T  = (unsigned short*)(wsb + 42270720);      //    262,144 B
    unsigned short* W2T  = (unsigned short*)(wsb + 42532864);      //    262,144 B
    unsigned short* WpT  = (unsigned short*)(wsb + 42795008);      //     65,536 B
    float*          csb  = (float*)(wsb + 42860544);               //     32,768 B
    float*          zrow = (float*)(wsb + 42893312);               //        256 B

    prep_kernel<<<576, 256, 0, stream>>>(W1, W2, Wp, W1T, W2T, WpT, zrow);
    enc_kernel<<<Vv / 64, 512, 0, stream>>>(embed, W1T, b1, W2T, b2,
                                            gamma, beta, WpT, bp, ptab);
    sprep_kernel<<<2048, 64, 0, stream>>>(seq, ptab, STg, qvec);
    scan_kernel<<<64, 64, 0, stream>>>(seq, ptab, STg, qvec, zrow, csb);
    out_kernel<<<Vv / 256, 256, 0, stream>>>(csb, Wo, bo, out);
}

// Round 4
// 343.525 us; speedup vs baseline: 9.1122x; 1.0810x over previous
//
#include <hip/hip_runtime.h>

#define Vv 32000
#define Ll 2048

typedef __bf16 bf16x8 __attribute__((ext_vector_type(8)));
typedef float  f32x4  __attribute__((ext_vector_type(4)));

__device__ __forceinline__ unsigned short f2bf(float f) {
    unsigned u = __builtin_bit_cast(unsigned, f);
    u += 0x7fffu + ((u >> 16) & 1u);
    return (unsigned short)(u >> 16);
}
__device__ __forceinline__ float bf2f(unsigned short s) {
    unsigned u = (unsigned)s << 16;
    return __builtin_bit_cast(float, u);
}
__device__ __forceinline__ void unpk8(uint4 v, float* o) {
    o[0] = bf2f((unsigned short)(v.x & 0xffff)); o[1] = bf2f((unsigned short)(v.x >> 16));
    o[2] = bf2f((unsigned short)(v.y & 0xffff)); o[3] = bf2f((unsigned short)(v.y >> 16));
    o[4] = bf2f((unsigned short)(v.z & 0xffff)); o[5] = bf2f((unsigned short)(v.z >> 16));
    o[6] = bf2f((unsigned short)(v.w & 0xffff)); o[7] = bf2f((unsigned short)(v.w >> 16));
}

#define MFMA(a, b, c) __builtin_amdgcn_mfma_f32_16x16x32_bf16(a, b, c, 0, 0, 0)
#define GLL16(gsrc, ldst)                                                    \
    __builtin_amdgcn_global_load_lds(                                        \
        (const __attribute__((address_space(1))) void*)(gsrc),               \
        (__attribute__((address_space(3))) void*)(ldst), 16, 0, 0)

// ---------------- prep: transpose W1/W2/Wp to bf16 [N][K]; zero pad row ----
__global__ __launch_bounds__(256) void prep_kernel(
    const float* __restrict__ W1, const float* __restrict__ W2,
    const float* __restrict__ Wp, unsigned short* __restrict__ W1T,
    unsigned short* __restrict__ W2T, unsigned short* __restrict__ WpT,
    float* __restrict__ zrow)
{
    int idx = blockIdx.x * 256 + threadIdx.x;   // pair index
    if (blockIdx.x == 575 && threadIdx.x < 64) zrow[threadIdx.x] = 0.f;
    if (idx < 65536) {                           // W1T [512][256] <- W1 [256][512]
        int e0 = idx * 2, n = e0 >> 8, k = e0 & 255;
        unsigned lo = f2bf(W1[(size_t)k * 512 + n]);
        unsigned hi = f2bf(W1[(size_t)(k + 1) * 512 + n]);
        ((unsigned*)W1T)[idx] = lo | (hi << 16);
    } else if (idx < 131072) {                   // W2T [256][512] <- W2 [512][256]
        int i = idx - 65536, e0 = i * 2, n = e0 >> 9, k = e0 & 511;
        unsigned lo = f2bf(W2[(size_t)k * 256 + n]);
        unsigned hi = f2bf(W2[(size_t)(k + 1) * 256 + n]);
        ((unsigned*)W2T)[i] = lo | (hi << 16);
    } else {                                     // WpT [128][256] <- Wp [256][128]
        int i = idx - 131072, e0 = i * 2, n = e0 >> 8, k = e0 & 255;
        unsigned lo = f2bf(Wp[(size_t)k * 128 + n]);
        unsigned hi = f2bf(Wp[(size_t)(k + 1) * 128 + n]);
        ((unsigned*)WpT)[i] = lo | (hi << 16);
    }
}

// ---------------- fused MFMA encoder over the VOCABULARY (32000 rows) ------
// 512 threads = 8 waves (2 M-groups x 4 N-groups), 64 vocab rows per block.
__global__ __launch_bounds__(512, 4) void enc_kernel(
    const float* __restrict__ embed,
    const unsigned short* __restrict__ W1T, const float* __restrict__ b1,
    const unsigned short* __restrict__ W2T, const float* __restrict__ b2,
    const float* __restrict__ gamma, const float* __restrict__ beta,
    const unsigned short* __restrict__ WpT, const float* __restrict__ bp,
    unsigned short* __restrict__ ptab)
{
    __shared__ char sE[64 * 512];      // bf16 [64][256], XOR-swizzled (e, then h)
    __shared__ char sU[64 * 256];      // bf16 [64][128], swizzled (U chunk) / plain (p stage)
    __shared__ float sPart[64][4][2];
    __shared__ float sMR[64][2];

    const int tid  = threadIdx.x;
    const int lane = tid & 63;
    const int w    = tid >> 6;
    const int wm   = w >> 2;           // 0..1
    const int wn   = w & 3;            // 0..3
    const int l15  = lane & 15;
    const int lk   = lane >> 4;        // 0..3
    const int n0   = blockIdx.x * 64;
    const int r0   = wm * 32;
    const int swl  = (l15 & 7) << 4;   // A-frag row swizzle (row&7 == l15&7)

    // ---- load E tile: identity rows (coalesced), f32 -> bf16 swizzled ----
    #pragma unroll
    for (int cc = 0; cc < 4; ++cc) {
        int c = cc * 512 + tid;          // 0..2047 16B-chunks
        int row  = c >> 5;
        int slot = (c & 31) << 4;
        int kbs  = slot ^ ((row & 7) << 4);
        const float* src = embed + (size_t)(n0 + row) * 256 + (kbs >> 1);
        float4 a = *(const float4*)src;
        float4 b = *(const float4*)(src + 4);
        uint4 pk;
        pk.x = (unsigned)f2bf(a.x) | ((unsigned)f2bf(a.y) << 16);
        pk.y = (unsigned)f2bf(a.z) | ((unsigned)f2bf(a.w) << 16);
        pk.z = (unsigned)f2bf(b.x) | ((unsigned)f2bf(b.y) << 16);
        pk.w = (unsigned)f2bf(b.z) | ((unsigned)f2bf(b.w) << 16);
        *(uint4*)(sE + row * 512 + slot) = pk;
    }
    __syncthreads();

    f32x4 acc2[2][4];
    #pragma unroll
    for (int i = 0; i < 2; ++i)
        #pragma unroll
        for (int j = 0; j < 4; ++j) acc2[i][j] = (f32x4){0.f, 0.f, 0.f, 0.f};

    #pragma unroll 1
    for (int c = 0; c < 4; ++c) {
        // ---- GEMM1 chunk: cols [c*128, c*128+128) ----
        f32x4 acc1[2][2];
        acc1[0][0] = acc1[0][1] = acc1[1][0] = acc1[1][1] = (f32x4){0.f, 0.f, 0.f, 0.f};
        const char* w1p = (const char*)W1T + (size_t)(c * 128 + wn * 32 + l15) * 512 + lk * 16;
        #pragma unroll
        for (int ks = 0; ks < 8; ++ks) {
            int ka = (ks * 64 + lk * 16) ^ swl;
            bf16x8 a0 = *(const bf16x8*)(sE + (r0 + l15) * 512 + ka);
            bf16x8 a1 = *(const bf16x8*)(sE + (r0 + 16 + l15) * 512 + ka);
            bf16x8 b0 = *(const bf16x8*)(w1p + ks * 64);
            bf16x8 b1 = *(const bf16x8*)(w1p + 16 * 512 + ks * 64);
            acc1[0][0] = MFMA(a0, b0, acc1[0][0]);
            acc1[1][0] = MFMA(a1, b0, acc1[1][0]);
            acc1[0][1] = MFMA(a0, b1, acc1[0][1]);
            acc1[1][1] = MFMA(a1, b1, acc1[1][1]);
        }
        float bv0 = b1[c * 128 + wn * 32 + l15];
        float bv1 = b1[c * 128 + wn * 32 + 16 + l15];
        #pragma unroll
        for (int mi = 0; mi < 2; ++mi)
            #pragma unroll
            for (int nj = 0; nj < 2; ++nj) {
                float bv = nj ? bv1 : bv0;
                #pragma unroll
                for (int r = 0; r < 4; ++r) {
                    int row  = r0 + mi * 16 + lk * 4 + r;
                    int coll = wn * 32 + nj * 16 + l15;
                    float v = fmaxf(acc1[mi][nj][r] + bv, 0.f);
                    *(unsigned short*)(sU + row * 256 + ((coll * 2) ^ ((row & 7) << 4))) = f2bf(v);
                }
            }
        __syncthreads();
        // ---- GEMM2 partial: k in [c*128, c*128+128) ----
        const char* w2p = (const char*)W2T + (size_t)(wn * 64 + l15) * 1024 + c * 256 + lk * 16;
        #pragma unroll
        for (int ks = 0; ks < 4; ++ks) {
            int ka = (ks * 64 + lk * 16) ^ swl;
            bf16x8 a0 = *(const bf16x8*)(sU + (r0 + l15) * 256 + ka);
            bf16x8 a1 = *(const bf16x8*)(sU + (r0 + 16 + l15) * 256 + ka);
            #pragma unroll
            for (int nj = 0; nj < 4; ++nj) {
                bf16x8 bb = *(const bf16x8*)(w2p + (size_t)nj * 16 * 1024 + ks * 64);
                acc2[0][nj] = MFMA(a0, bb, acc2[0][nj]);
                acc2[1][nj] = MFMA(a1, bb, acc2[1][nj]);
            }
        }
        __syncthreads();
    }

    // ---- x = e(bf16 from LDS) + f + b2 ; LN stats ----
    float b2v[4], gv[4], btv[4];
    #pragma unroll
    for (int nj = 0; nj < 4; ++nj) {
        int col = wn * 64 + nj * 16 + l15;
        b2v[nj] = b2[col]; gv[nj] = gamma[col]; btv[nj] = beta[col];
    }
    #pragma unroll
    for (int mi = 0; mi < 2; ++mi)
        #pragma unroll
        for (int r = 0; r < 4; ++r) {
            int row = r0 + mi * 16 + lk * 4 + r;
            int swr = (row & 7) << 4;
            float s1 = 0.f, s2 = 0.f;
            #pragma unroll
            for (int nj = 0; nj < 4; ++nj) {
                int col = wn * 64 + nj * 16 + l15;
                float e = bf2f(*(const unsigned short*)(sE + row * 512 + ((col * 2) ^ swr)));
                float x = acc2[mi][nj][r] + b2v[nj] + e;
                acc2[mi][nj][r] = x;
                s1 += x; s2 = fmaf(x, x, s2);
            }
            s1 += __shfl_xor(s1, 1); s2 += __shfl_xor(s2, 1);
            s1 += __shfl_xor(s1, 2); s2 += __shfl_xor(s2, 2);
            s1 += __shfl_xor(s1, 4); s2 += __shfl_xor(s2, 4);
            s1 += __shfl_xor(s1, 8); s2 += __shfl_xor(s2, 8);
            if (l15 == 0) { sPart[row][wn][0] = s1; sPart[row][wn][1] = s2; }
        }
    __syncthreads();
    if (tid < 64) {
        float t1 = sPart[tid][0][0] + sPart[tid][1][0] + sPart[tid][2][0] + sPart[tid][3][0];
        float t2 = sPart[tid][0][1] + sPart[tid][1][1] + sPart[tid][2][1] + sPart[tid][3][1];
        float mu  = t1 * (1.f / 256.f);
        float var = t2 * (1.f / 256.f) - mu * mu;
        sMR[tid][0] = mu;
        sMR[tid][1] = rsqrtf(var + 1e-5f);
    }
    __syncthreads();
    // ---- h -> sE (bf16, swizzled) ----
    #pragma unroll
    for (int mi = 0; mi < 2; ++mi)
        #pragma unroll
        for (int r = 0; r < 4; ++r) {
            int row = r0 + mi * 16 + lk * 4 + r;
            int swr = (row & 7) << 4;
            float mu = sMR[row][0], rs = sMR[row][1];
            #pragma unroll
            for (int nj = 0; nj < 4; ++nj) {
                int col = wn * 64 + nj * 16 + l15;
                float h = (acc2[mi][nj][r] - mu) * rs * gv[nj] + btv[nj];
                *(unsigned short*)(sE + row * 512 + ((col * 2) ^ swr)) = f2bf(h);
            }
        }
    __syncthreads();

    // ---- GEMM3: p = h @ WpT^T + bp ----
    f32x4 acc3[2][2];
    acc3[0][0] = acc3[0][1] = acc3[1][0] = acc3[1][1] = (f32x4){0.f, 0.f, 0.f, 0.f};
    const char* wpp = (const char*)WpT + (size_t)(wn * 32 + l15) * 512 + lk * 16;
    #pragma unroll
    for (int ks = 0; ks < 8; ++ks) {
        int ka = (ks * 64 + lk * 16) ^ swl;
        bf16x8 a0 = *(const bf16x8*)(sE + (r0 + l15) * 512 + ka);
        bf16x8 a1 = *(const bf16x8*)(sE + (r0 + 16 + l15) * 512 + ka);
        bf16x8 b0 = *(const bf16x8*)(wpp + ks * 64);
        bf16x8 b1 = *(const bf16x8*)(wpp + 16 * 512 + ks * 64);
        acc3[0][0] = MFMA(a0, b0, acc3[0][0]);
        acc3[1][0] = MFMA(a1, b0, acc3[1][0]);
        acc3[0][1] = MFMA(a0, b1, acc3[0][1]);
        acc3[1][1] = MFMA(a1, b1, acc3[1][1]);
    }
    float bp0 = bp[wn * 32 + l15], bp1 = bp[wn * 32 + 16 + l15];
    #pragma unroll
    for (int mi = 0; mi < 2; ++mi)
        #pragma unroll
        for (int nj = 0; nj < 2; ++nj)
            #pragma unroll
            for (int r = 0; r < 4; ++r) {
                int row = r0 + mi * 16 + lk * 4 + r;
                int col = wn * 32 + nj * 16 + l15;
                *(unsigned short*)(sU + row * 256 + col * 2) =
                    f2bf(acc3[mi][nj][r] + (nj ? bp1 : bp0));
            }
    __syncthreads();
    #pragma unroll
    for (int ii = 0; ii < 2; ++ii) {
        int idx = tid * 2 + ii;            // 0..1023
        int row = idx >> 4, slot = (idx & 15) << 4;
        *(uint4*)((char*)ptab + (size_t)(n0 + row) * 256 + slot) =
            *(const uint4*)(sU + row * 256 + slot);
    }
}

// ---------------- sprep v2: per-chunk Gram only, transposed store ----------
// One wave per (batch, chunk). Writes GT[i][j] = G[j][i] for the lower
// triangle blocks of G (j >= i valid); no LDS, fragments straight from ptab.
__global__ __launch_bounds__(64) void sprep_kernel(
    const int* __restrict__ seq, const unsigned short* __restrict__ ptab,
    float* __restrict__ GTg)
{
    const int blk  = blockIdx.x;               // 0..2047
    const int b    = blk >> 5, ch = blk & 31;
    const int t_hi = 2047 - (ch << 6);
    const int lane = threadIdx.x;
    const int l15  = lane & 15, lk = lane >> 4;

    int v = seq[b * 2048 + t_hi - lane];       // row `lane` of this chunk
    int vr[4];
    #pragma unroll
    for (int t4 = 0; t4 < 4; ++t4)
        vr[t4] = __shfl(v, t4 * 16 + l15);

    const bool zpad = (ch == 0) && (l15 == 0);   // row 0 == query pad (t=2047)
    uint4 zz; zz.x = zz.y = zz.z = zz.w = 0u;
    const bf16x8 fz = __builtin_bit_cast(bf16x8, zz);

    f32x4 acc[10];
    #pragma unroll
    for (int q = 0; q < 10; ++q) acc[q] = (f32x4){0.f, 0.f, 0.f, 0.f};

    #pragma unroll
    for (int ks = 0; ks < 4; ++ks) {
        bf16x8 fr[4];
        #pragma unroll
        for (int t4 = 0; t4 < 4; ++t4)
            fr[t4] = *(const bf16x8*)((const char*)ptab +
                       (size_t)vr[t4] * 256 + ks * 64 + lk * 16);
        if (zpad) fr[0] = fz;
        int q = 0;
        #pragma unroll
        for (int ti = 0; ti < 4; ++ti)
            #pragma unroll
            for (int tj = 0; tj <= ti; ++tj, ++q)
                acc[q] = MFMA(fr[ti], fr[tj], acc[q]);
    }

    // D[r=(lk*4+reg)][c=l15] of G-block (ti,tj)  ->  GT[tj*16+l15][ti*16+lk*4+reg]
    float* base = GTg + ((size_t)blk << 12);
    int q = 0;
    #pragma unroll
    for (int ti = 0; ti < 4; ++ti)
        #pragma unroll
        for (int tj = 0; tj <= ti; ++tj, ++q)
            *(f32x4*)(base + (tj * 16 + l15) * 64 + ti * 16 + lk * 4) = acc[q];
}

// ---------------- serial chunked scan: 1 wave per batch, in-scan solve -----
__global__ __launch_bounds__(64) void scan_kernel(
    const int* __restrict__ seq, const unsigned short* __restrict__ ptab,
    const float* __restrict__ GTg, const float* __restrict__ zrow,
    float* __restrict__ csb)
{
    __shared__ int sSeq[2048];
    __shared__ unsigned short sKb[2][8192];   // [64][128] bf16, linear
    __shared__ float sGT[2][4096];            // GT[i][j] = G[j][i]
    __shared__ float sU[128];
    __shared__ float sBQ[64];
    __shared__ float sQI[64];
    __shared__ float sZC[128];                // (z_i, c_i)

    const int b = blockIdx.x;
    const int lane = threadIdx.x;

    #pragma unroll
    for (int r = 0; r < 8; ++r)
        *(int4*)&sSeq[r * 256 + lane * 4] = *(const int4*)&seq[b * 2048 + r * 256 + lane * 4];
    {
        int vq = seq[b * 2048 + 2047];
        unsigned pk = *(const unsigned*)(ptab + (size_t)vq * 128 + lane * 2);
        sU[lane * 2]     = bf2f((unsigned short)(pk & 0xffff));
        sU[lane * 2 + 1] = bf2f((unsigned short)(pk >> 16));
    }
    float csv0 = 0.f, csv1 = 0.f;
    __syncthreads();

    auto STAGE = [&](int s, int ch) {          // 32 global_load_lds per call
        int t_hi = 2047 - (ch << 6);
        #pragma unroll
        for (int k = 0; k < 16; ++k) {
            int g = k * 64 + lane;
            int r = g >> 4, sd = g & 15;
            int t = t_hi - r;
            int v = sSeq[t];
            const char* srow = (t == 2047) ? (const char*)zrow
                                           : (const char*)(ptab + (size_t)v * 128);
            GLL16(srow + sd * 16, (char*)sKb[s] + k * 1024);
        }
        const char* gts = (const char*)(GTg + (((size_t)b * 32 + ch) << 12));
        #pragma unroll
        for (int k = 0; k < 16; ++k)
            GLL16(gts + k * 1024 + lane * 16, (char*)sGT[s] + k * 1024);
    };

    STAGE(0, 0); STAGE(1, 1);

    #pragma unroll 1
    for (int c = 0; c < 32; ++c) {
        const int cur = c & 1;
        if (c < 31) { asm volatile("s_waitcnt vmcnt(32)" ::: "memory"); }
        else        { asm volatile("s_waitcnt vmcnt(0)"  ::: "memory"); }
        __builtin_amdgcn_sched_barrier(0);

        const unsigned short* kb = sKb[cur];
        const float* gtb = sGT[cur];

        // phase A: b_i = k_i . u  (lane = i; XOR slot order for banks)
        float av[4] = {0.f, 0.f, 0.f, 0.f};
        const int swl = lane & 15;
        #pragma unroll
        for (int ss = 0; ss < 16; ++ss) {
            int jj = ss ^ swl;
            uint4 kv = *(const uint4*)((const char*)kb + lane * 256 + jj * 16);
            f32x4 ua = *(const f32x4*)&sU[jj * 8];
            f32x4 ub = *(const f32x4*)&sU[jj * 8 + 4];
            float kf[8]; unpk8(kv, kf);
            float& a = av[ss & 3];
            a = fmaf(kf[0], ua.x, a); a = fmaf(kf[1], ua.y, a);
            a = fmaf(kf[2], ua.z, a); a = fmaf(kf[3], ua.w, a);
            a = fmaf(kf[4], ub.x, a); a = fmaf(kf[5], ub.y, a);
            a = fmaf(kf[6], ub.z, a); a = fmaf(kf[7], ub.w, a);
        }
        float bl = (av[0] + av[1]) + (av[2] + av[3]);

        // per-lane diag + exact reciprocal (off the serial chain)
        float di = gtb[lane * 65] + 1e-6f;     // GT[i][i] = G[i][i]
        float qi = 1.f / di;
        sBQ[lane] = bl * qi;
        sQI[lane] = qi;
        __syncthreads();

        // solve (D+L) z = b, rank-1 right-looking; lane = r
        float pacc = 0.f, zm = 0.f;
        #pragma unroll
        for (int i = 0; i < 64; ++i) {
            float p  = __shfl(pacc, i);
            float zi = fmaf(-p, sQI[i], sBQ[i]);
            zm = (lane == i) ? zi : zm;
            pacc = fmaf(gtb[i * 64 + lane], zi, pacc);
        }
        sZC[lane * 2]     = zm;
        sZC[lane * 2 + 1] = zm * di;
        __syncthreads();

        // phase C: u -= K^T z ; cs += K^T c   (lane owns d = 2*lane, 2*lane+1)
        float du0a = 0.f, du0b = 0.f, du1a = 0.f, du1b = 0.f;
        float dc0a = 0.f, dc0b = 0.f, dc1a = 0.f, dc1b = 0.f;
        #pragma unroll 8
        for (int i = 0; i < 32; ++i) {
            unsigned kp = *(const unsigned*)((const char*)kb + i * 256 + lane * 4);
            float2 zc = *(const float2*)&sZC[i * 2];
            float k0 = bf2f((unsigned short)(kp & 0xffff));
            float k1 = bf2f((unsigned short)(kp >> 16));
            du0a = fmaf(zc.x, k0, du0a); du1a = fmaf(zc.x, k1, du1a);
            dc0a = fmaf(zc.y, k0, dc0a); dc1a = fmaf(zc.y, k1, dc1a);
        }
        #pragma unroll 8
        for (int i = 32; i < 64; ++i) {
            unsigned kp = *(const unsigned*)((const char*)kb + i * 256 + lane * 4);
            float2 zc = *(const float2*)&sZC[i * 2];
            float k0 = bf2f((unsigned short)(kp & 0xffff));
            float k1 = bf2f((unsigned short)(kp >> 16));
            du0b = fmaf(zc.x, k0, du0b); du1b = fmaf(zc.x, k1, du1b);
            dc0b = fmaf(zc.y, k0, dc0b); dc1b = fmaf(zc.y, k1, dc1b);
        }
        sU[lane * 2]     = sU[lane * 2]     - (du0a + du0b);
        sU[lane * 2 + 1] = sU[lane * 2 + 1] - (du1a + du1b);
        csv0 += dc0a + dc0b;
        csv1 += dc1a + dc1b;

        if (c + 2 < 32) STAGE(cur, c + 2);
        __syncthreads();
    }
    csb[b * 128 + lane * 2]     = csv0;
    csb[b * 128 + lane * 2 + 1] = csv1;
}

// ---------------- out = cs @ Wo + bo : [64,128]@[128,32000] ----------------
__global__ __launch_bounds__(256) void out_kernel(
    const float* __restrict__ cs, const float* __restrict__ Wo,
    const float* __restrict__ bo, float* __restrict__ out)
{
    __shared__ float sC[64 * 128];
    const int tid = threadIdx.x;
    #pragma unroll
    for (int r = 0; r < 8; ++r)
        ((float4*)sC)[r * 256 + tid] = ((const float4*)cs)[r * 256 + tid];
    __syncthreads();

    const int j = blockIdx.x * 256 + tid;
    float acc[64];
    #pragma unroll
    for (int r = 0; r < 64; ++r) acc[r] = 0.f;
    for (int k0 = 0; k0 < 128; k0 += 4) {
        float w0 = Wo[(size_t)(k0 + 0) * Vv + j];
        float w1 = Wo[(size_t)(k0 + 1) * Vv + j];
        float w2 = Wo[(size_t)(k0 + 2) * Vv + j];
        float w3 = Wo[(size_t)(k0 + 3) * Vv + j];
        #pragma unroll
        for (int r = 0; r < 64; ++r) {
            float4 c = *(const float4*)&sC[r * 128 + k0];
            acc[r] = fmaf(c.x, w0, fmaf(c.y, w1, fmaf(c.z, w2, fmaf(c.w, w3, acc[r]))));
        }
    }
    float bj = bo[j];
    #pragma unroll
    for (int r = 0; r < 64; ++r)
        out[(size_t)r * Vv + j] = acc[r] + bj;
}

extern "C" void kernel_launch(void* const* d_in, const int* in_sizes, int n_in,
                              void* d_out, int out_size, void* d_ws, size_t ws_size,
                              hipStream_t stream)
{
    const int*   seq   = (const int*)  d_in[0];
    const float* embed = (const float*)d_in[1];
    const float* W1    = (const float*)d_in[2];
    const float* b1    = (const float*)d_in[3];
    const float* W2    = (const float*)d_in[4];
    const float* b2    = (const float*)d_in[5];
    const float* gamma = (const float*)d_in[6];
    const float* beta  = (const float*)d_in[7];
    const float* Wp    = (const float*)d_in[8];
    const float* bp    = (const float*)d_in[9];
    const float* Wo    = (const float*)d_in[10];
    const float* bo    = (const float*)d_in[11];
    float* out = (float*)d_out;

    char* wsb = (char*)d_ws;
    unsigned short* ptab = (unsigned short*)(wsb);                 //  8,192,000 B
    float*          GTg  = (float*)(wsb + 8192000);                // 33,554,432 B
    unsigned short* W1T  = (unsigned short*)(wsb + 41746432);      //    262,144 B
    unsigned short* W2T  = (unsigned short*)(wsb + 42008576);      //    262,144 B
    unsigned short* WpT  = (unsigned short*)(wsb + 42270720);      //     65,536 B
    float*          csb  = (float*)(wsb + 42336256);               //     32,768 B
    float*          zrow = (float*)(wsb + 42369024);               //        256 B

    prep_kernel<<<576, 256, 0, stream>>>(W1, W2, Wp, W1T, W2T, WpT, zrow);
    enc_kernel<<<Vv / 64, 512, 0, stream>>>(embed, W1T, b1, W2T, b2,
                                            gamma, beta, WpT, bp, ptab);
    sprep_kernel<<<2048, 64, 0, stream>>>(seq, ptab, GTg);
    scan_kernel<<<64, 64, 0, stream>>>(seq, ptab, GTg, zrow, csb);
    out_kernel<<<Vv / 256, 256, 0, stream>>>(csb, Wo, bo, out);
}

// Round 5
// 317.611 us; speedup vs baseline: 9.8556x; 1.0816x over previous
//
#include <hip/hip_runtime.h>

#define Vv 32000
#define Ll 2048

typedef __bf16 bf16x8 __attribute__((ext_vector_type(8)));
typedef float  f32x4  __attribute__((ext_vector_type(4)));

__device__ __forceinline__ unsigned short f2bf(float f) {
    unsigned u = __builtin_bit_cast(unsigned, f);
    u += 0x7fffu + ((u >> 16) & 1u);
    return (unsigned short)(u >> 16);
}
__device__ __forceinline__ float bf2f(unsigned short s) {
    unsigned u = (unsigned)s << 16;
    return __builtin_bit_cast(float, u);
}
__device__ __forceinline__ void unpk8(uint4 v, float* o) {
    o[0] = bf2f((unsigned short)(v.x & 0xffff)); o[1] = bf2f((unsigned short)(v.x >> 16));
    o[2] = bf2f((unsigned short)(v.y & 0xffff)); o[3] = bf2f((unsigned short)(v.y >> 16));
    o[4] = bf2f((unsigned short)(v.z & 0xffff)); o[5] = bf2f((unsigned short)(v.z >> 16));
    o[6] = bf2f((unsigned short)(v.w & 0xffff)); o[7] = bf2f((unsigned short)(v.w >> 16));
}

#define MFMA(a, b, c) __builtin_amdgcn_mfma_f32_16x16x32_bf16(a, b, c, 0, 0, 0)
#define GLL16(gsrc, ldst)                                                    \
    __builtin_amdgcn_global_load_lds(                                        \
        (const __attribute__((address_space(1))) void*)(gsrc),               \
        (__attribute__((address_space(3))) void*)(ldst), 16, 0, 0)

// ---------------- prep: transpose W1/W2/Wp to bf16 [N][K]; zero pad row ----
__global__ __launch_bounds__(256) void prep_kernel(
    const float* __restrict__ W1, const float* __restrict__ W2,
    const float* __restrict__ Wp, unsigned short* __restrict__ W1T,
    unsigned short* __restrict__ W2T, unsigned short* __restrict__ WpT,
    float* __restrict__ zrow)
{
    int idx = blockIdx.x * 256 + threadIdx.x;   // pair index
    if (blockIdx.x == 575 && threadIdx.x < 64) zrow[threadIdx.x] = 0.f;
    if (idx < 65536) {                           // W1T [512][256] <- W1 [256][512]
        int e0 = idx * 2, n = e0 >> 8, k = e0 & 255;
        unsigned lo = f2bf(W1[(size_t)k * 512 + n]);
        unsigned hi = f2bf(W1[(size_t)(k + 1) * 512 + n]);
        ((unsigned*)W1T)[idx] = lo | (hi << 16);
    } else if (idx < 131072) {                   // W2T [256][512] <- W2 [512][256]
        int i = idx - 65536, e0 = i * 2, n = e0 >> 9, k = e0 & 511;
        unsigned lo = f2bf(W2[(size_t)k * 256 + n]);
        unsigned hi = f2bf(W2[(size_t)(k + 1) * 256 + n]);
        ((unsigned*)W2T)[i] = lo | (hi << 16);
    } else {                                     // WpT [128][256] <- Wp [256][128]
        int i = idx - 131072, e0 = i * 2, n = e0 >> 8, k = e0 & 255;
        unsigned lo = f2bf(Wp[(size_t)k * 128 + n]);
        unsigned hi = f2bf(Wp[(size_t)(k + 1) * 128 + n]);
        ((unsigned*)WpT)[i] = lo | (hi << 16);
    }
}

// ---------------- fused MFMA encoder over the VOCABULARY (32000 rows) ------
// 512 threads = 8 waves (2 M-groups x 4 N-groups), 64 vocab rows per block.
__global__ __launch_bounds__(512, 4) void enc_kernel(
    const float* __restrict__ embed,
    const unsigned short* __restrict__ W1T, const float* __restrict__ b1,
    const unsigned short* __restrict__ W2T, const float* __restrict__ b2,
    const float* __restrict__ gamma, const float* __restrict__ beta,
    const unsigned short* __restrict__ WpT, const float* __restrict__ bp,
    unsigned short* __restrict__ ptab)
{
    __shared__ char sE[64 * 512];      // bf16 [64][256], XOR-swizzled (e, then h)
    __shared__ char sU[64 * 256];      // bf16 [64][128], swizzled (U chunk) / plain (p stage)
    __shared__ float sPart[64][4][2];
    __shared__ float sMR[64][2];

    const int tid  = threadIdx.x;
    const int lane = tid & 63;
    const int w    = tid >> 6;
    const int wm   = w >> 2;           // 0..1
    const int wn   = w & 3;            // 0..3
    const int l15  = lane & 15;
    const int lk   = lane >> 4;        // 0..3
    const int n0   = blockIdx.x * 64;
    const int r0   = wm * 32;
    const int swl  = (l15 & 7) << 4;   // A-frag row swizzle (row&7 == l15&7)

    // ---- load E tile: identity rows (coalesced), f32 -> bf16 swizzled ----
    #pragma unroll
    for (int cc = 0; cc < 4; ++cc) {
        int c = cc * 512 + tid;          // 0..2047 16B-chunks
        int row  = c >> 5;
        int slot = (c & 31) << 4;
        int kbs  = slot ^ ((row & 7) << 4);
        const float* src = embed + (size_t)(n0 + row) * 256 + (kbs >> 1);
        float4 a = *(const float4*)src;
        float4 b = *(const float4*)(src + 4);
        uint4 pk;
        pk.x = (unsigned)f2bf(a.x) | ((unsigned)f2bf(a.y) << 16);
        pk.y = (unsigned)f2bf(a.z) | ((unsigned)f2bf(a.w) << 16);
        pk.z = (unsigned)f2bf(b.x) | ((unsigned)f2bf(b.y) << 16);
        pk.w = (unsigned)f2bf(b.z) | ((unsigned)f2bf(b.w) << 16);
        *(uint4*)(sE + row * 512 + slot) = pk;
    }
    __syncthreads();

    f32x4 acc2[2][4];
    #pragma unroll
    for (int i = 0; i < 2; ++i)
        #pragma unroll
        for (int j = 0; j < 4; ++j) acc2[i][j] = (f32x4){0.f, 0.f, 0.f, 0.f};

    #pragma unroll 1
    for (int c = 0; c < 4; ++c) {
        // ---- GEMM1 chunk: cols [c*128, c*128+128) ----
        f32x4 acc1[2][2];
        acc1[0][0] = acc1[0][1] = acc1[1][0] = acc1[1][1] = (f32x4){0.f, 0.f, 0.f, 0.f};
        const char* w1p = (const char*)W1T + (size_t)(c * 128 + wn * 32 + l15) * 512 + lk * 16;
        #pragma unroll
        for (int ks = 0; ks < 8; ++ks) {
            int ka = (ks * 64 + lk * 16) ^ swl;
            bf16x8 a0 = *(const bf16x8*)(sE + (r0 + l15) * 512 + ka);
            bf16x8 a1 = *(const bf16x8*)(sE + (r0 + 16 + l15) * 512 + ka);
            bf16x8 b0 = *(const bf16x8*)(w1p + ks * 64);
            bf16x8 b1 = *(const bf16x8*)(w1p + 16 * 512 + ks * 64);
            acc1[0][0] = MFMA(a0, b0, acc1[0][0]);
            acc1[1][0] = MFMA(a1, b0, acc1[1][0]);
            acc1[0][1] = MFMA(a0, b1, acc1[0][1]);
            acc1[1][1] = MFMA(a1, b1, acc1[1][1]);
        }
        float bv0 = b1[c * 128 + wn * 32 + l15];
        float bv1 = b1[c * 128 + wn * 32 + 16 + l15];
        #pragma unroll
        for (int mi = 0; mi < 2; ++mi)
            #pragma unroll
            for (int nj = 0; nj < 2; ++nj) {
                float bv = nj ? bv1 : bv0;
                #pragma unroll
                for (int r = 0; r < 4; ++r) {
                    int row  = r0 + mi * 16 + lk * 4 + r;
                    int coll = wn * 32 + nj * 16 + l15;
                    float v = fmaxf(acc1[mi][nj][r] + bv, 0.f);
                    *(unsigned short*)(sU + row * 256 + ((coll * 2) ^ ((row & 7) << 4))) = f2bf(v);
                }
            }
        __syncthreads();
        // ---- GEMM2 partial: k in [c*128, c*128+128) ----
        const char* w2p = (const char*)W2T + (size_t)(wn * 64 + l15) * 1024 + c * 256 + lk * 16;
        #pragma unroll
        for (int ks = 0; ks < 4; ++ks) {
            int ka = (ks * 64 + lk * 16) ^ swl;
            bf16x8 a0 = *(const bf16x8*)(sU + (r0 + l15) * 256 + ka);
            bf16x8 a1 = *(const bf16x8*)(sU + (r0 + 16 + l15) * 256 + ka);
            #pragma unroll
            for (int nj = 0; nj < 4; ++nj) {
                bf16x8 bb = *(const bf16x8*)(w2p + (size_t)nj * 16 * 1024 + ks * 64);
                acc2[0][nj] = MFMA(a0, bb, acc2[0][nj]);
                acc2[1][nj] = MFMA(a1, bb, acc2[1][nj]);
            }
        }
        __syncthreads();
    }

    // ---- x = e(bf16 from LDS) + f + b2 ; LN stats ----
    float b2v[4], gv[4], btv[4];
    #pragma unroll
    for (int nj = 0; nj < 4; ++nj) {
        int col = wn * 64 + nj * 16 + l15;
        b2v[nj] = b2[col]; gv[nj] = gamma[col]; btv[nj] = beta[col];
    }
    #pragma unroll
    for (int mi = 0; mi < 2; ++mi)
        #pragma unroll
        for (int r = 0; r < 4; ++r) {
            int row = r0 + mi * 16 + lk * 4 + r;
            int swr = (row & 7) << 4;
            float s1 = 0.f, s2 = 0.f;
            #pragma unroll
            for (int nj = 0; nj < 4; ++nj) {
                int col = wn * 64 + nj * 16 + l15;
                float e = bf2f(*(const unsigned short*)(sE + row * 512 + ((col * 2) ^ swr)));
                float x = acc2[mi][nj][r] + b2v[nj] + e;
                acc2[mi][nj][r] = x;
                s1 += x; s2 = fmaf(x, x, s2);
            }
            s1 += __shfl_xor(s1, 1); s2 += __shfl_xor(s2, 1);
            s1 += __shfl_xor(s1, 2); s2 += __shfl_xor(s2, 2);
            s1 += __shfl_xor(s1, 4); s2 += __shfl_xor(s2, 4);
            s1 += __shfl_xor(s1, 8); s2 += __shfl_xor(s2, 8);
            if (l15 == 0) { sPart[row][wn][0] = s1; sPart[row][wn][1] = s2; }
        }
    __syncthreads();
    if (tid < 64) {
        float t1 = sPart[tid][0][0] + sPart[tid][1][0] + sPart[tid][2][0] + sPart[tid][3][0];
        float t2 = sPart[tid][0][1] + sPart[tid][1][1] + sPart[tid][2][1] + sPart[tid][3][1];
        float mu  = t1 * (1.f / 256.f);
        float var = t2 * (1.f / 256.f) - mu * mu;
        sMR[tid][0] = mu;
        sMR[tid][1] = rsqrtf(var + 1e-5f);
    }
    __syncthreads();
    // ---- h -> sE (bf16, swizzled) ----
    #pragma unroll
    for (int mi = 0; mi < 2; ++mi)
        #pragma unroll
        for (int r = 0; r < 4; ++r) {
            int row = r0 + mi * 16 + lk * 4 + r;
            int swr = (row & 7) << 4;
            float mu = sMR[row][0], rs = sMR[row][1];
            #pragma unroll
            for (int nj = 0; nj < 4; ++nj) {
                int col = wn * 64 + nj * 16 + l15;
                float h = (acc2[mi][nj][r] - mu) * rs * gv[nj] + btv[nj];
                *(unsigned short*)(sE + row * 512 + ((col * 2) ^ swr)) = f2bf(h);
            }
        }
    __syncthreads();

    // ---- GEMM3: p = h @ WpT^T + bp ----
    f32x4 acc3[2][2];
    acc3[0][0] = acc3[0][1] = acc3[1][0] = acc3[1][1] = (f32x4){0.f, 0.f, 0.f, 0.f};
    const char* wpp = (const char*)WpT + (size_t)(wn * 32 + l15) * 512 + lk * 16;
    #pragma unroll
    for (int ks = 0; ks < 8; ++ks) {
        int ka = (ks * 64 + lk * 16) ^ swl;
        bf16x8 a0 = *(const bf16x8*)(sE + (r0 + l15) * 512 + ka);
        bf16x8 a1 = *(const bf16x8*)(sE + (r0 + 16 + l15) * 512 + ka);
        bf16x8 b0 = *(const bf16x8*)(wpp + ks * 64);
        bf16x8 b1 = *(const bf16x8*)(wpp + 16 * 512 + ks * 64);
        acc3[0][0] = MFMA(a0, b0, acc3[0][0]);
        acc3[1][0] = MFMA(a1, b0, acc3[1][0]);
        acc3[0][1] = MFMA(a0, b1, acc3[0][1]);
        acc3[1][1] = MFMA(a1, b1, acc3[1][1]);
    }
    float bp0 = bp[wn * 32 + l15], bp1 = bp[wn * 32 + 16 + l15];
    #pragma unroll
    for (int mi = 0; mi < 2; ++mi)
        #pragma unroll
        for (int nj = 0; nj < 2; ++nj)
            #pragma unroll
            for (int r = 0; r < 4; ++r) {
                int row = r0 + mi * 16 + lk * 4 + r;
                int col = wn * 32 + nj * 16 + l15;
                *(unsigned short*)(sU + row * 256 + col * 2) =
                    f2bf(acc3[mi][nj][r] + (nj ? bp1 : bp0));
            }
    __syncthreads();
    #pragma unroll
    for (int ii = 0; ii < 2; ++ii) {
        int idx = tid * 2 + ii;            // 0..1023
        int row = idx >> 4, slot = (idx & 15) << 4;
        *(uint4*)((char*)ptab + (size_t)(n0 + row) * 256 + slot) =
            *(const uint4*)(sU + row * 256 + slot);
    }
}

// ---------------- sprep v3: Gram + block-inverse + W = (D+L)^-1 K ----------
// One wave per (batch, chunk). Blob out (17408 B/chunk):
//   [0,16384): WTP[d2=64][i=64] u32 = packed bf16 pair (W[i][2d2], W[i][2d2+1])
//   [16384, 16640): diag[64] f32 (d_i = G_ii + eps); rest pad.
__global__ __launch_bounds__(64) void sprep_kernel(
    const int* __restrict__ seq, const unsigned short* __restrict__ ptab,
    char* __restrict__ SBg)
{
    __shared__ unsigned short sK[64 * 136];   // 17408 B, rows 272 B
    __shared__ float sG[10 * 16 * 17];        // 10880 B, block-major [q][r][c]
    __shared__ float sM[4 * 16 * 17];         //  4352 B
    __shared__ float sQ[64];                  //   256 B
    __shared__ float sW[64 * 132];            // 33792 B, rows 528 B

    const int blk  = blockIdx.x;              // 0..2047
    const int b    = blk >> 5, ch = blk & 31;
    const int t_hi = 2047 - (ch << 6);
    const int lane = threadIdx.x;
    const int l15  = lane & 15, lk = lane >> 4;

    // ---- stage K rows (lane = row i, t = t_hi - i); zero the query pad ----
    {
        int t = t_hi - lane;
        if (t == 2047) {
            #pragma unroll
            for (int j = 0; j < 16; ++j)
                *(uint4*)((char*)sK + lane * 272 + j * 16) = (uint4){0u, 0u, 0u, 0u};
        } else {
            int v = seq[b * 2048 + t];
            const char* src = (const char*)(ptab + (size_t)v * 128);
            #pragma unroll
            for (int j = 0; j < 16; ++j)
                *(uint4*)((char*)sK + lane * 272 + j * 16) = *(const uint4*)(src + j * 16);
        }
    }
    __syncthreads();

    // ---- Gram lower blocks via MFMA ----
    f32x4 acc[10];
    #pragma unroll
    for (int q = 0; q < 10; ++q) acc[q] = (f32x4){0.f, 0.f, 0.f, 0.f};
    #pragma unroll
    for (int ks = 0; ks < 4; ++ks) {
        bf16x8 fr[4];
        #pragma unroll
        for (int t4 = 0; t4 < 4; ++t4)
            fr[t4] = *(const bf16x8*)((const char*)sK + (t4 * 16 + l15) * 272 + ks * 64 + lk * 16);
        int q = 0;
        #pragma unroll
        for (int ti = 0; ti < 4; ++ti)
            #pragma unroll
            for (int tj = 0; tj <= ti; ++tj, ++q)
                acc[q] = MFMA(fr[ti], fr[tj], acc[q]);
    }
    {
        int q = 0;
        #pragma unroll
        for (int ti = 0; ti < 4; ++ti)
            #pragma unroll
            for (int tj = 0; tj <= ti; ++tj, ++q)
                #pragma unroll
                for (int r = 0; r < 4; ++r)
                    sG[q * 272 + (lk * 4 + r) * 17 + l15] = acc[q][r];
    }
    __syncthreads();

    // ---- reciprocals of diagonal (lane = (g = lk, row = l15)) ----
    {
        int dq = (lk * (lk + 3)) >> 1;            // diag block q-index
        float d = sG[dq * 272 + l15 * 17 + l15] + 1e-6f;
        sQ[lane] = 1.0f / d;
    }
    __syncthreads();

    // ---- invert 4 diagonal blocks: group g = lk, column c = l15 ----
    {
        const int g = lk, c = l15;
        const float* Tg = &sG[((g * (g + 3)) >> 1) * 272];
        float qv[16], av[16], mcol[16];
        #pragma unroll
        for (int r = 0; r < 16; ++r) { qv[r] = sQ[g * 16 + r]; av[r] = 0.f; }
        #pragma unroll
        for (int r = 0; r < 16; ++r) {
            float mr = (((r == c) ? 1.f : 0.f) - av[r]) * qv[r];
            mcol[r] = mr;
            #pragma unroll
            for (int i = r + 1; i < 16; ++i)
                av[i] = fmaf(Tg[i * 17 + r], mr, av[i]);
        }
        #pragma unroll
        for (int r = 0; r < 16; ++r)
            sM[g * 272 + r * 17 + c] = mcol[r];
    }
    __syncthreads();

    // ---- W build: lane = (rr = l15 row-in-block, dqt = lk d-quarter) ----
    const int rr = l15, dqt = lk;
    #pragma unroll 1
    for (int s = 0; s < 4; ++s) {
        float a[32];
        {   // init from K row 16s+rr, cols [dqt*32, +32)
            const char* kr = (const char*)sK + (16 * s + rr) * 272 + dqt * 64;
            #pragma unroll
            for (int v = 0; v < 4; ++v) {
                uint4 kv = *(const uint4*)(kr + v * 16);
                unpk8(kv, &a[v * 8]);
            }
        }
        #pragma unroll
        for (int j = 0; j < 3; ++j) {           // subtract T_sj @ W_j, j < s
            if (j >= s) break;
            const float* Tb = &sG[(((s * (s + 1)) >> 1) + j) * 272];
            #pragma unroll
            for (int m = 0; m < 16; ++m) {
                float t = Tb[rr * 17 + m];
                const float* wrow = &sW[(16 * j + m) * 132 + dqt * 32];
                #pragma unroll
                for (int v = 0; v < 8; ++v) {
                    f32x4 wv = *(const f32x4*)(wrow + v * 4);
                    a[v * 4 + 0] = fmaf(-t, wv.x, a[v * 4 + 0]);
                    a[v * 4 + 1] = fmaf(-t, wv.y, a[v * 4 + 1]);
                    a[v * 4 + 2] = fmaf(-t, wv.z, a[v * 4 + 2]);
                    a[v * 4 + 3] = fmaf(-t, wv.w, a[v * 4 + 3]);
                }
            }
        }
        {   // write tmp rows of block s
            float* wrow = &sW[(16 * s + rr) * 132 + dqt * 32];
            #pragma unroll
            for (int v = 0; v < 8; ++v) {
                f32x4 wv = {a[v * 4 + 0], a[v * 4 + 1], a[v * 4 + 2], a[v * 4 + 3]};
                *(f32x4*)(wrow + v * 4) = wv;
            }
        }
        __syncthreads();
        float o[32];
        #pragma unroll
        for (int v = 0; v < 32; ++v) o[v] = 0.f;
        #pragma unroll
        for (int cc = 0; cc < 16; ++cc) {       // W_s = M_s @ tmp
            float mm = sM[s * 272 + rr * 17 + cc];
            const float* wrow = &sW[(16 * s + cc) * 132 + dqt * 32];
            #pragma unroll
            for (int v = 0; v < 8; ++v) {
                f32x4 wv = *(const f32x4*)(wrow + v * 4);
                o[v * 4 + 0] = fmaf(mm, wv.x, o[v * 4 + 0]);
                o[v * 4 + 1] = fmaf(mm, wv.y, o[v * 4 + 1]);
                o[v * 4 + 2] = fmaf(mm, wv.z, o[v * 4 + 2]);
                o[v * 4 + 3] = fmaf(mm, wv.w, o[v * 4 + 3]);
            }
        }
        __syncthreads();                        // all tmp reads done
        {   // overwrite block-s rows with final W_s
            float* wrow = &sW[(16 * s + rr) * 132 + dqt * 32];
            #pragma unroll
            for (int v = 0; v < 8; ++v) {
                f32x4 wv = {o[v * 4 + 0], o[v * 4 + 1], o[v * 4 + 2], o[v * 4 + 3]};
                *(f32x4*)(wrow + v * 4) = wv;
            }
        }
        __syncthreads();
    }

    // ---- write WTP (transposed, packed bf16) + diag ----
    char* blob = SBg + (size_t)blk * 17408;
    unsigned* wtp = (unsigned*)blob;
    #pragma unroll 8
    for (int d2 = 0; d2 < 64; ++d2) {
        float2 wv = *(const float2*)&sW[lane * 132 + d2 * 2];
        wtp[d2 * 64 + lane] = (unsigned)f2bf(wv.x) | ((unsigned)f2bf(wv.y) << 16);
    }
    {
        int dq = (lk * (lk + 3)) >> 1;
        float d = sG[dq * 272 + l15 * 17 + l15] + 1e-6f;
        *(float*)(blob + 16384 + lane * 4) = d;
    }
}

// ---------------- serial chunked scan: z = W u, u -= K^T z, cs += K^T(Dz) --
__global__ __launch_bounds__(64) void scan_kernel(
    const int* __restrict__ seq, const unsigned short* __restrict__ ptab,
    const char* __restrict__ SBg, const float* __restrict__ zrow,
    float* __restrict__ csb)
{
    __shared__ int sSeq[2048];
    __shared__ unsigned short sKb[2][8192];   // [64][128] bf16, linear
    __shared__ char sBlob[2][17408];          // WTP + diag
    __shared__ float sU[128];
    __shared__ float sZC[128];                // (z_i, c_i)

    const int b = blockIdx.x;
    const int lane = threadIdx.x;

    #pragma unroll
    for (int r = 0; r < 8; ++r)
        *(int4*)&sSeq[r * 256 + lane * 4] = *(const int4*)&seq[b * 2048 + r * 256 + lane * 4];
    {
        int vq = seq[b * 2048 + 2047];
        unsigned pk = *(const unsigned*)(ptab + (size_t)vq * 128 + lane * 2);
        sU[lane * 2]     = bf2f((unsigned short)(pk & 0xffff));
        sU[lane * 2 + 1] = bf2f((unsigned short)(pk >> 16));
    }
    float csv0 = 0.f, csv1 = 0.f;
    __syncthreads();

    auto STAGE = [&](int s, int ch) {          // 33 global_load_lds per call
        int t_hi = 2047 - (ch << 6);
        #pragma unroll
        for (int k = 0; k < 16; ++k) {
            int g = k * 64 + lane;
            int r = g >> 4, sd = g & 15;
            int t = t_hi - r;
            int v = sSeq[t];
            const char* srow = (t == 2047) ? (const char*)zrow
                                           : (const char*)(ptab + (size_t)v * 128);
            GLL16(srow + sd * 16, (char*)sKb[s] + k * 1024);
        }
        const char* bsrc = SBg + ((size_t)b * 32 + ch) * 17408;
        #pragma unroll
        for (int k = 0; k < 17; ++k)
            GLL16(bsrc + k * 1024 + lane * 16, (char*)sBlob[s] + k * 1024);
    };

    STAGE(0, 0); STAGE(1, 1);

    #pragma unroll 1
    for (int c = 0; c < 32; ++c) {
        const int cur = c & 1;
        if (c < 31) { asm volatile("s_waitcnt vmcnt(33)" ::: "memory"); }
        else        { asm volatile("s_waitcnt vmcnt(0)"  ::: "memory"); }
        __builtin_amdgcn_sched_barrier(0);

        const unsigned short* kb = sKb[cur];
        const unsigned* wt = (const unsigned*)(sBlob[cur]);
        const float* dgv = (const float*)(sBlob[cur] + 16384);

        // phase Z: z_i = W[i][:] . u   (lane = i; conflict-free reads)
        float za = 0.f, zb = 0.f;
        #pragma unroll
        for (int d2 = 0; d2 < 64; ++d2) {
            unsigned wp = wt[d2 * 64 + lane];
            float2 uv = *(const float2*)&sU[d2 * 2];
            za = fmaf(bf2f((unsigned short)(wp & 0xffff)), uv.x, za);
            zb = fmaf(bf2f((unsigned short)(wp >> 16)),    uv.y, zb);
        }
        float z  = za + zb;
        float ci = z * dgv[lane];
        sZC[lane * 2]     = z;
        sZC[lane * 2 + 1] = ci;
        __syncthreads();

        // phase C: u -= K^T z ; cs += K^T c   (lane owns d = 2*lane, 2*lane+1)
        float du0a = 0.f, du0b = 0.f, du1a = 0.f, du1b = 0.f;
        float dc0a = 0.f, dc0b = 0.f, dc1a = 0.f, dc1b = 0.f;
        #pragma unroll 8
        for (int i = 0; i < 32; ++i) {
            unsigned kp = *(const unsigned*)((const char*)kb + i * 256 + lane * 4);
            float2 zc = *(const float2*)&sZC[i * 2];
            float k0 = bf2f((unsigned short)(kp & 0xffff));
            float k1 = bf2f((unsigned short)(kp >> 16));
            du0a = fmaf(zc.x, k0, du0a); du1a = fmaf(zc.x, k1, du1a);
            dc0a = fmaf(zc.y, k0, dc0a); dc1a = fmaf(zc.y, k1, dc1a);
        }
        #pragma unroll 8
        for (int i = 32; i < 64; ++i) {
            unsigned kp = *(const unsigned*)((const char*)kb + i * 256 + lane * 4);
            float2 zc = *(const float2*)&sZC[i * 2];
            float k0 = bf2f((unsigned short)(kp & 0xffff));
            float k1 = bf2f((unsigned short)(kp >> 16));
            du0b = fmaf(zc.x, k0, du0b); du1b = fmaf(zc.x, k1, du1b);
            dc0b = fmaf(zc.y, k0, dc0b); dc1b = fmaf(zc.y, k1, dc1b);
        }
        sU[lane * 2]     = sU[lane * 2]     - (du0a + du0b);
        sU[lane * 2 + 1] = sU[lane * 2 + 1] - (du1a + du1b);
        csv0 += dc0a + dc0b;
        csv1 += dc1a + dc1b;

        if (c + 2 < 32) STAGE(cur, c + 2);
        __syncthreads();
    }
    csb[b * 128 + lane * 2]     = csv0;
    csb[b * 128 + lane * 2 + 1] = csv1;
}

// ---------------- out = cs @ Wo + bo : [64,128]@[128,32000] ----------------
__global__ __launch_bounds__(256) void out_kernel(
    const float* __restrict__ cs, const float* __restrict__ Wo,
    const float* __restrict__ bo, float* __restrict__ out)
{
    __shared__ float sC[64 * 128];
    const int tid = threadIdx.x;
    #pragma unroll
    for (int r = 0; r < 8; ++r)
        ((float4*)sC)[r * 256 + tid] = ((const float4*)cs)[r * 256 + tid];
    __syncthreads();

    const int j = blockIdx.x * 256 + tid;
    float acc[64];
    #pragma unroll
    for (int r = 0; r < 64; ++r) acc[r] = 0.f;
    for (int k0 = 0; k0 < 128; k0 += 4) {
        float w0 = Wo[(size_t)(k0 + 0) * Vv + j];
        float w1 = Wo[(size_t)(k0 + 1) * Vv + j];
        float w2 = Wo[(size_t)(k0 + 2) * Vv + j];
        float w3 = Wo[(size_t)(k0 + 3) * Vv + j];
        #pragma unroll
        for (int r = 0; r < 64; ++r) {
            float4 c = *(const float4*)&sC[r * 128 + k0];
            acc[r] = fmaf(c.x, w0, fmaf(c.y, w1, fmaf(c.z, w2, fmaf(c.w, w3, acc[r]))));
        }
    }
    float bj = bo[j];
    #pragma unroll
    for (int r = 0; r < 64; ++r)
        out[(size_t)r * Vv + j] = acc[r] + bj;
}

extern "C" void kernel_launch(void* const* d_in, const int* in_sizes, int n_in,
                              void* d_out, int out_size, void* d_ws, size_t ws_size,
                              hipStream_t stream)
{
    const int*   seq   = (const int*)  d_in[0];
    const float* embed = (const float*)d_in[1];
    const float* W1    = (const float*)d_in[2];
    const float* b1    = (const float*)d_in[3];
    const float* W2    = (const float*)d_in[4];
    const float* b2    = (const float*)d_in[5];
    const float* gamma = (const float*)d_in[6];
    const float* beta  = (const float*)d_in[7];
    const float* Wp    = (const float*)d_in[8];
    const float* bp    = (const float*)d_in[9];
    const float* Wo    = (const float*)d_in[10];
    const float* bo    = (const float*)d_in[11];
    float* out = (float*)d_out;

    char* wsb = (char*)d_ws;
    unsigned short* ptab = (unsigned short*)(wsb);                 //  8,192,000 B
    char*           SBg  = wsb + 8192000;                          // 35,651,584 B
    unsigned short* W1T  = (unsigned short*)(wsb + 43843584);      //    262,144 B
    unsigned short* W2T  = (unsigned short*)(wsb + 44105728);      //    262,144 B
    unsigned short* WpT  = (unsigned short*)(wsb + 44367872);      //     65,536 B
    float*          csb  = (float*)(wsb + 44433408);               //     32,768 B
    float*          zrow = (float*)(wsb + 44466176);               //        256 B

    prep_kernel<<<576, 256, 0, stream>>>(W1, W2, Wp, W1T, W2T, WpT, zrow);
    enc_kernel<<<Vv / 64, 512, 0, stream>>>(embed, W1T, b1, W2T, b2,
                                            gamma, beta, WpT, bp, ptab);
    sprep_kernel<<<2048, 64, 0, stream>>>(seq, ptab, SBg);
    scan_kernel<<<64, 64, 0, stream>>>(seq, ptab, SBg, zrow, csb);
    out_kernel<<<Vv / 256, 256, 0, stream>>>(csb, Wo, bo, out);
}

// Round 6
// 315.261 us; speedup vs baseline: 9.9291x; 1.0075x over previous
//
#include <hip/hip_runtime.h>

#define Vv 32000
#define Ll 2048

typedef __bf16 bf16x8 __attribute__((ext_vector_type(8)));
typedef float  f32x4  __attribute__((ext_vector_type(4)));

__device__ __forceinline__ unsigned short f2bf(float f) {
    unsigned u = __builtin_bit_cast(unsigned, f);
    u += 0x7fffu + ((u >> 16) & 1u);
    return (unsigned short)(u >> 16);
}
__device__ __forceinline__ float bf2f(unsigned short s) {
    unsigned u = (unsigned)s << 16;
    return __builtin_bit_cast(float, u);
}
__device__ __forceinline__ void unpk8(uint4 v, float* o) {
    o[0] = bf2f((unsigned short)(v.x & 0xffff)); o[1] = bf2f((unsigned short)(v.x >> 16));
    o[2] = bf2f((unsigned short)(v.y & 0xffff)); o[3] = bf2f((unsigned short)(v.y >> 16));
    o[4] = bf2f((unsigned short)(v.z & 0xffff)); o[5] = bf2f((unsigned short)(v.z >> 16));
    o[6] = bf2f((unsigned short)(v.w & 0xffff)); o[7] = bf2f((unsigned short)(v.w >> 16));
}

#define MFMA(a, b, c) __builtin_amdgcn_mfma_f32_16x16x32_bf16(a, b, c, 0, 0, 0)
#define GLL16(gsrc, ldst)                                                    \
    __builtin_amdgcn_global_load_lds(                                        \
        (const __attribute__((address_space(1))) void*)(gsrc),               \
        (__attribute__((address_space(3))) void*)(ldst), 16, 0, 0)

// ---------------- prep: transpose W1/W2/Wp to bf16 [N][K]; zero pad row ----
__global__ __launch_bounds__(256) void prep_kernel(
    const float* __restrict__ W1, const float* __restrict__ W2,
    const float* __restrict__ Wp, unsigned short* __restrict__ W1T,
    unsigned short* __restrict__ W2T, unsigned short* __restrict__ WpT,
    float* __restrict__ zrow)
{
    int idx = blockIdx.x * 256 + threadIdx.x;   // pair index
    if (blockIdx.x == 575 && threadIdx.x < 64) zrow[threadIdx.x] = 0.f;
    if (idx < 65536) {                           // W1T [512][256] <- W1 [256][512]
        int e0 = idx * 2, n = e0 >> 8, k = e0 & 255;
        unsigned lo = f2bf(W1[(size_t)k * 512 + n]);
        unsigned hi = f2bf(W1[(size_t)(k + 1) * 512 + n]);
        ((unsigned*)W1T)[idx] = lo | (hi << 16);
    } else if (idx < 131072) {                   // W2T [256][512] <- W2 [512][256]
        int i = idx - 65536, e0 = i * 2, n = e0 >> 9, k = e0 & 511;
        unsigned lo = f2bf(W2[(size_t)k * 256 + n]);
        unsigned hi = f2bf(W2[(size_t)(k + 1) * 256 + n]);
        ((unsigned*)W2T)[i] = lo | (hi << 16);
    } else {                                     // WpT [128][256] <- Wp [256][128]
        int i = idx - 131072, e0 = i * 2, n = e0 >> 8, k = e0 & 255;
        unsigned lo = f2bf(Wp[(size_t)k * 128 + n]);
        unsigned hi = f2bf(Wp[(size_t)(k + 1) * 128 + n]);
        ((unsigned*)WpT)[i] = lo | (hi << 16);
    }
}

// ---------------- fused MFMA encoder over the VOCABULARY (32000 rows) ------
// 512 threads = 8 waves (2 M-groups x 4 N-groups), 64 vocab rows per block.
__global__ __launch_bounds__(512, 4) void enc_kernel(
    const float* __restrict__ embed,
    const unsigned short* __restrict__ W1T, const float* __restrict__ b1,
    const unsigned short* __restrict__ W2T, const float* __restrict__ b2,
    const float* __restrict__ gamma, const float* __restrict__ beta,
    const unsigned short* __restrict__ WpT, const float* __restrict__ bp,
    unsigned short* __restrict__ ptab)
{
    __shared__ char sE[64 * 512];      // bf16 [64][256], XOR-swizzled (e, then h)
    __shared__ char sU[64 * 256];      // bf16 [64][128], swizzled (U chunk) / plain (p stage)
    __shared__ float sPart[64][4][2];
    __shared__ float sMR[64][2];

    const int tid  = threadIdx.x;
    const int lane = tid & 63;
    const int w    = tid >> 6;
    const int wm   = w >> 2;           // 0..1
    const int wn   = w & 3;            // 0..3
    const int l15  = lane & 15;
    const int lk   = lane >> 4;        // 0..3
    const int n0   = blockIdx.x * 64;
    const int r0   = wm * 32;
    const int swl  = (l15 & 7) << 4;   // A-frag row swizzle (row&7 == l15&7)

    // ---- load E tile: identity rows (coalesced), f32 -> bf16 swizzled ----
    #pragma unroll
    for (int cc = 0; cc < 4; ++cc) {
        int c = cc * 512 + tid;          // 0..2047 16B-chunks
        int row  = c >> 5;
        int slot = (c & 31) << 4;
        int kbs  = slot ^ ((row & 7) << 4);
        const float* src = embed + (size_t)(n0 + row) * 256 + (kbs >> 1);
        float4 a = *(const float4*)src;
        float4 b = *(const float4*)(src + 4);
        uint4 pk;
        pk.x = (unsigned)f2bf(a.x) | ((unsigned)f2bf(a.y) << 16);
        pk.y = (unsigned)f2bf(a.z) | ((unsigned)f2bf(a.w) << 16);
        pk.z = (unsigned)f2bf(b.x) | ((unsigned)f2bf(b.y) << 16);
        pk.w = (unsigned)f2bf(b.z) | ((unsigned)f2bf(b.w) << 16);
        *(uint4*)(sE + row * 512 + slot) = pk;
    }
    __syncthreads();

    f32x4 acc2[2][4];
    #pragma unroll
    for (int i = 0; i < 2; ++i)
        #pragma unroll
        for (int j = 0; j < 4; ++j) acc2[i][j] = (f32x4){0.f, 0.f, 0.f, 0.f};

    #pragma unroll 1
    for (int c = 0; c < 4; ++c) {
        // ---- GEMM1 chunk: cols [c*128, c*128+128) ----
        f32x4 acc1[2][2];
        acc1[0][0] = acc1[0][1] = acc1[1][0] = acc1[1][1] = (f32x4){0.f, 0.f, 0.f, 0.f};
        const char* w1p = (const char*)W1T + (size_t)(c * 128 + wn * 32 + l15) * 512 + lk * 16;
        #pragma unroll
        for (int ks = 0; ks < 8; ++ks) {
            int ka = (ks * 64 + lk * 16) ^ swl;
            bf16x8 a0 = *(const bf16x8*)(sE + (r0 + l15) * 512 + ka);
            bf16x8 a1 = *(const bf16x8*)(sE + (r0 + 16 + l15) * 512 + ka);
            bf16x8 b0 = *(const bf16x8*)(w1p + ks * 64);
            bf16x8 b1 = *(const bf16x8*)(w1p + 16 * 512 + ks * 64);
            acc1[0][0] = MFMA(a0, b0, acc1[0][0]);
            acc1[1][0] = MFMA(a1, b0, acc1[1][0]);
            acc1[0][1] = MFMA(a0, b1, acc1[0][1]);
            acc1[1][1] = MFMA(a1, b1, acc1[1][1]);
        }
        float bv0 = b1[c * 128 + wn * 32 + l15];
        float bv1 = b1[c * 128 + wn * 32 + 16 + l15];
        #pragma unroll
        for (int mi = 0; mi < 2; ++mi)
            #pragma unroll
            for (int nj = 0; nj < 2; ++nj) {
                float bv = nj ? bv1 : bv0;
                #pragma unroll
                for (int r = 0; r < 4; ++r) {
                    int row  = r0 + mi * 16 + lk * 4 + r;
                    int coll = wn * 32 + nj * 16 + l15;
                    float v = fmaxf(acc1[mi][nj][r] + bv, 0.f);
                    *(unsigned short*)(sU + row * 256 + ((coll * 2) ^ ((row & 7) << 4))) = f2bf(v);
                }
            }
        __syncthreads();
        // ---- GEMM2 partial: k in [c*128, c*128+128) ----
        const char* w2p = (const char*)W2T + (size_t)(wn * 64 + l15) * 1024 + c * 256 + lk * 16;
        #pragma unroll
        for (int ks = 0; ks < 4; ++ks) {
            int ka = (ks * 64 + lk * 16) ^ swl;
            bf16x8 a0 = *(const bf16x8*)(sU + (r0 + l15) * 256 + ka);
            bf16x8 a1 = *(const bf16x8*)(sU + (r0 + 16 + l15) * 256 + ka);
            #pragma unroll
            for (int nj = 0; nj < 4; ++nj) {
                bf16x8 bb = *(const bf16x8*)(w2p + (size_t)nj * 16 * 1024 + ks * 64);
                acc2[0][nj] = MFMA(a0, bb, acc2[0][nj]);
                acc2[1][nj] = MFMA(a1, bb, acc2[1][nj]);
            }
        }
        __syncthreads();
    }

    // ---- x = e(bf16 from LDS) + f + b2 ; LN stats ----
    float b2v[4], gv[4], btv[4];
    #pragma unroll
    for (int nj = 0; nj < 4; ++nj) {
        int col = wn * 64 + nj * 16 + l15;
        b2v[nj] = b2[col]; gv[nj] = gamma[col]; btv[nj] = beta[col];
    }
    #pragma unroll
    for (int mi = 0; mi < 2; ++mi)
        #pragma unroll
        for (int r = 0; r < 4; ++r) {
            int row = r0 + mi * 16 + lk * 4 + r;
            int swr = (row & 7) << 4;
            float s1 = 0.f, s2 = 0.f;
            #pragma unroll
            for (int nj = 0; nj < 4; ++nj) {
                int col = wn * 64 + nj * 16 + l15;
                float e = bf2f(*(const unsigned short*)(sE + row * 512 + ((col * 2) ^ swr)));
                float x = acc2[mi][nj][r] + b2v[nj] + e;
                acc2[mi][nj][r] = x;
                s1 += x; s2 = fmaf(x, x, s2);
            }
            s1 += __shfl_xor(s1, 1); s2 += __shfl_xor(s2, 1);
            s1 += __shfl_xor(s1, 2); s2 += __shfl_xor(s2, 2);
            s1 += __shfl_xor(s1, 4); s2 += __shfl_xor(s2, 4);
            s1 += __shfl_xor(s1, 8); s2 += __shfl_xor(s2, 8);
            if (l15 == 0) { sPart[row][wn][0] = s1; sPart[row][wn][1] = s2; }
        }
    __syncthreads();
    if (tid < 64) {
        float t1 = sPart[tid][0][0] + sPart[tid][1][0] + sPart[tid][2][0] + sPart[tid][3][0];
        float t2 = sPart[tid][0][1] + sPart[tid][1][1] + sPart[tid][2][1] + sPart[tid][3][1];
        float mu  = t1 * (1.f / 256.f);
        float var = t2 * (1.f / 256.f) - mu * mu;
        sMR[tid][0] = mu;
        sMR[tid][1] = rsqrtf(var + 1e-5f);
    }
    __syncthreads();
    // ---- h -> sE (bf16, swizzled) ----
    #pragma unroll
    for (int mi = 0; mi < 2; ++mi)
        #pragma unroll
        for (int r = 0; r < 4; ++r) {
            int row = r0 + mi * 16 + lk * 4 + r;
            int swr = (row & 7) << 4;
            float mu = sMR[row][0], rs = sMR[row][1];
            #pragma unroll
            for (int nj = 0; nj < 4; ++nj) {
                int col = wn * 64 + nj * 16 + l15;
                float h = (acc2[mi][nj][r] - mu) * rs * gv[nj] + btv[nj];
                *(unsigned short*)(sE + row * 512 + ((col * 2) ^ swr)) = f2bf(h);
            }
        }
    __syncthreads();

    // ---- GEMM3: p = h @ WpT^T + bp ----
    f32x4 acc3[2][2];
    acc3[0][0] = acc3[0][1] = acc3[1][0] = acc3[1][1] = (f32x4){0.f, 0.f, 0.f, 0.f};
    const char* wpp = (const char*)WpT + (size_t)(wn * 32 + l15) * 512 + lk * 16;
    #pragma unroll
    for (int ks = 0; ks < 8; ++ks) {
        int ka = (ks * 64 + lk * 16) ^ swl;
        bf16x8 a0 = *(const bf16x8*)(sE + (r0 + l15) * 512 + ka);
        bf16x8 a1 = *(const bf16x8*)(sE + (r0 + 16 + l15) * 512 + ka);
        bf16x8 b0 = *(const bf16x8*)(wpp + ks * 64);
        bf16x8 b1 = *(const bf16x8*)(wpp + 16 * 512 + ks * 64);
        acc3[0][0] = MFMA(a0, b0, acc3[0][0]);
        acc3[1][0] = MFMA(a1, b0, acc3[1][0]);
        acc3[0][1] = MFMA(a0, b1, acc3[0][1]);
        acc3[1][1] = MFMA(a1, b1, acc3[1][1]);
    }
    float bp0 = bp[wn * 32 + l15], bp1 = bp[wn * 32 + 16 + l15];
    #pragma unroll
    for (int mi = 0; mi < 2; ++mi)
        #pragma unroll
        for (int nj = 0; nj < 2; ++nj)
            #pragma unroll
            for (int r = 0; r < 4; ++r) {
                int row = r0 + mi * 16 + lk * 4 + r;
                int col = wn * 32 + nj * 16 + l15;
                *(unsigned short*)(sU + row * 256 + col * 2) =
                    f2bf(acc3[mi][nj][r] + (nj ? bp1 : bp0));
            }
    __syncthreads();
    #pragma unroll
    for (int ii = 0; ii < 2; ++ii) {
        int idx = tid * 2 + ii;            // 0..1023
        int row = idx >> 4, slot = (idx & 15) << 4;
        *(uint4*)((char*)ptab + (size_t)(n0 + row) * 256 + slot) =
            *(const uint4*)(sU + row * 256 + slot);
    }
}

// ---------------- sprep v3: Gram + block-inverse + W = (D+L)^-1 K ----------
// One wave per (batch, chunk). Blob out (17408 B/chunk):
//   [0,16384): WTP[d2=64][i=64] u32 = packed bf16 pair (W[i][2d2], W[i][2d2+1])
//   [16384, 16640): diag[64] f32 (d_i = G_ii + eps); rest pad.
__global__ __launch_bounds__(64) void sprep_kernel(
    const int* __restrict__ seq, const unsigned short* __restrict__ ptab,
    char* __restrict__ SBg)
{
    __shared__ unsigned short sK[64 * 136];   // 17408 B, rows 272 B
    __shared__ float sG[10 * 16 * 17];        // 10880 B, block-major [q][r][c]
    __shared__ float sM[4 * 16 * 17];         //  4352 B
    __shared__ float sQ[64];                  //   256 B
    __shared__ float sW[64 * 132];            // 33792 B, rows 528 B

    const int blk  = blockIdx.x;              // 0..2047
    const int b    = blk >> 5, ch = blk & 31;
    const int t_hi = 2047 - (ch << 6);
    const int lane = threadIdx.x;
    const int l15  = lane & 15, lk = lane >> 4;

    // ---- stage K rows (lane = row i, t = t_hi - i); zero the query pad ----
    {
        int t = t_hi - lane;
        if (t == 2047) {
            #pragma unroll
            for (int j = 0; j < 16; ++j)
                *(uint4*)((char*)sK + lane * 272 + j * 16) = (uint4){0u, 0u, 0u, 0u};
        } else {
            int v = seq[b * 2048 + t];
            const char* src = (const char*)(ptab + (size_t)v * 128);
            #pragma unroll
            for (int j = 0; j < 16; ++j)
                *(uint4*)((char*)sK + lane * 272 + j * 16) = *(const uint4*)(src + j * 16);
        }
    }
    __syncthreads();

    // ---- Gram lower blocks via MFMA ----
    f32x4 acc[10];
    #pragma unroll
    for (int q = 0; q < 10; ++q) acc[q] = (f32x4){0.f, 0.f, 0.f, 0.f};
    #pragma unroll
    for (int ks = 0; ks < 4; ++ks) {
        bf16x8 fr[4];
        #pragma unroll
        for (int t4 = 0; t4 < 4; ++t4)
            fr[t4] = *(const bf16x8*)((const char*)sK + (t4 * 16 + l15) * 272 + ks * 64 + lk * 16);
        int q = 0;
        #pragma unroll
        for (int ti = 0; ti < 4; ++ti)
            #pragma unroll
            for (int tj = 0; tj <= ti; ++tj, ++q)
                acc[q] = MFMA(fr[ti], fr[tj], acc[q]);
    }
    {
        int q = 0;
        #pragma unroll
        for (int ti = 0; ti < 4; ++ti)
            #pragma unroll
            for (int tj = 0; tj <= ti; ++tj, ++q)
                #pragma unroll
                for (int r = 0; r < 4; ++r)
                    sG[q * 272 + (lk * 4 + r) * 17 + l15] = acc[q][r];
    }
    __syncthreads();

    // ---- reciprocals of diagonal (lane = (g = lk, row = l15)) ----
    {
        int dq = (lk * (lk + 3)) >> 1;            // diag block q-index
        float d = sG[dq * 272 + l15 * 17 + l15] + 1e-6f;
        sQ[lane] = 1.0f / d;
    }
    __syncthreads();

    // ---- invert 4 diagonal blocks: group g = lk, column c = l15 ----
    {
        const int g = lk, c = l15;
        const float* Tg = &sG[((g * (g + 3)) >> 1) * 272];
        float qv[16], av[16], mcol[16];
        #pragma unroll
        for (int r = 0; r < 16; ++r) { qv[r] = sQ[g * 16 + r]; av[r] = 0.f; }
        #pragma unroll
        for (int r = 0; r < 16; ++r) {
            float mr = (((r == c) ? 1.f : 0.f) - av[r]) * qv[r];
            mcol[r] = mr;
            #pragma unroll
            for (int i = r + 1; i < 16; ++i)
                av[i] = fmaf(Tg[i * 17 + r], mr, av[i]);
        }
        #pragma unroll
        for (int r = 0; r < 16; ++r)
            sM[g * 272 + r * 17 + c] = mcol[r];
    }
    __syncthreads();

    // ---- W build: lane = (rr = l15 row-in-block, dqt = lk d-quarter) ----
    const int rr = l15, dqt = lk;
    #pragma unroll 1
    for (int s = 0; s < 4; ++s) {
        float a[32];
        {   // init from K row 16s+rr, cols [dqt*32, +32)
            const char* kr = (const char*)sK + (16 * s + rr) * 272 + dqt * 64;
            #pragma unroll
            for (int v = 0; v < 4; ++v) {
                uint4 kv = *(const uint4*)(kr + v * 16);
                unpk8(kv, &a[v * 8]);
            }
        }
        #pragma unroll
        for (int j = 0; j < 3; ++j) {           // subtract T_sj @ W_j, j < s
            if (j >= s) break;
            const float* Tb = &sG[(((s * (s + 1)) >> 1) + j) * 272];
            #pragma unroll
            for (int m = 0; m < 16; ++m) {
                float t = Tb[rr * 17 + m];
                const float* wrow = &sW[(16 * j + m) * 132 + dqt * 32];
                #pragma unroll
                for (int v = 0; v < 8; ++v) {
                    f32x4 wv = *(const f32x4*)(wrow + v * 4);
                    a[v * 4 + 0] = fmaf(-t, wv.x, a[v * 4 + 0]);
                    a[v * 4 + 1] = fmaf(-t, wv.y, a[v * 4 + 1]);
                    a[v * 4 + 2] = fmaf(-t, wv.z, a[v * 4 + 2]);
                    a[v * 4 + 3] = fmaf(-t, wv.w, a[v * 4 + 3]);
                }
            }
        }
        {   // write tmp rows of block s
            float* wrow = &sW[(16 * s + rr) * 132 + dqt * 32];
            #pragma unroll
            for (int v = 0; v < 8; ++v) {
                f32x4 wv = {a[v * 4 + 0], a[v * 4 + 1], a[v * 4 + 2], a[v * 4 + 3]};
                *(f32x4*)(wrow + v * 4) = wv;
            }
        }
        __syncthreads();
        float o[32];
        #pragma unroll
        for (int v = 0; v < 32; ++v) o[v] = 0.f;
        #pragma unroll
        for (int cc = 0; cc < 16; ++cc) {       // W_s = M_s @ tmp
            float mm = sM[s * 272 + rr * 17 + cc];
            const float* wrow = &sW[(16 * s + cc) * 132 + dqt * 32];
            #pragma unroll
            for (int v = 0; v < 8; ++v) {
                f32x4 wv = *(const f32x4*)(wrow + v * 4);
                o[v * 4 + 0] = fmaf(mm, wv.x, o[v * 4 + 0]);
                o[v * 4 + 1] = fmaf(mm, wv.y, o[v * 4 + 1]);
                o[v * 4 + 2] = fmaf(mm, wv.z, o[v * 4 + 2]);
                o[v * 4 + 3] = fmaf(mm, wv.w, o[v * 4 + 3]);
            }
        }
        __syncthreads();                        // all tmp reads done
        {   // overwrite block-s rows with final W_s
            float* wrow = &sW[(16 * s + rr) * 132 + dqt * 32];
            #pragma unroll
            for (int v = 0; v < 8; ++v) {
                f32x4 wv = {o[v * 4 + 0], o[v * 4 + 1], o[v * 4 + 2], o[v * 4 + 3]};
                *(f32x4*)(wrow + v * 4) = wv;
            }
        }
        __syncthreads();
    }

    // ---- write WTP (transposed, packed bf16) + diag ----
    char* blob = SBg + (size_t)blk * 17408;
    unsigned* wtp = (unsigned*)blob;
    #pragma unroll 8
    for (int d2 = 0; d2 < 64; ++d2) {
        float2 wv = *(const float2*)&sW[lane * 132 + d2 * 2];
        wtp[d2 * 64 + lane] = (unsigned)f2bf(wv.x) | ((unsigned)f2bf(wv.y) << 16);
    }
    {
        int dq = (lk * (lk + 3)) >> 1;
        float d = sG[dq * 272 + l15 * 17 + l15] + 1e-6f;
        *(float*)(blob + 16384 + lane * 4) = d;
    }
}

// ---------------- serial chunked scan: z = W u, u -= K^T z, cs += K^T(Dz) --
// Single wave per block: NO __syncthreads in the loop (it would emit
// s_waitcnt vmcnt(0) and drain the prefetch DMA). Cross-lane LDS traffic
// within one wave only needs the compiler's automatic lgkmcnt waits.
__global__ __launch_bounds__(64) void scan_kernel(
    const int* __restrict__ seq, const unsigned short* __restrict__ ptab,
    const char* __restrict__ SBg, const float* __restrict__ zrow,
    float* __restrict__ csb)
{
    __shared__ int sSeq[2048];
    __shared__ unsigned short sKb[2][8192];   // [64][128] bf16, linear
    __shared__ char sBlob[2][17408];          // WTP + diag
    __shared__ float sU[128];
    __shared__ float sZC[128];                // (z_i, c_i)

    const int b = blockIdx.x;
    const int lane = threadIdx.x;

    #pragma unroll
    for (int r = 0; r < 8; ++r)
        *(int4*)&sSeq[r * 256 + lane * 4] = *(const int4*)&seq[b * 2048 + r * 256 + lane * 4];
    {
        int vq = seq[b * 2048 + 2047];
        unsigned pk = *(const unsigned*)(ptab + (size_t)vq * 128 + lane * 2);
        sU[lane * 2]     = bf2f((unsigned short)(pk & 0xffff));
        sU[lane * 2 + 1] = bf2f((unsigned short)(pk >> 16));
    }
    float csv0 = 0.f, csv1 = 0.f;
    __syncthreads();   // once, before the loop (drains the init loads)

    auto STAGE = [&](int s, int ch) {          // 33 global_load_lds per call
        int t_hi = 2047 - (ch << 6);
        #pragma unroll
        for (int k = 0; k < 16; ++k) {
            int g = k * 64 + lane;
            int r = g >> 4, sd = g & 15;
            int t = t_hi - r;
            int v = sSeq[t];
            const char* srow = (t == 2047) ? (const char*)zrow
                                           : (const char*)(ptab + (size_t)v * 128);
            GLL16(srow + sd * 16, (char*)sKb[s] + k * 1024);
        }
        const char* bsrc = SBg + ((size_t)b * 32 + ch) * 17408;
        #pragma unroll
        for (int k = 0; k < 17; ++k)
            GLL16(bsrc + k * 1024 + lane * 16, (char*)sBlob[s] + k * 1024);
    };

    STAGE(0, 0); STAGE(1, 1);

    #pragma unroll 1
    for (int c = 0; c < 32; ++c) {
        const int cur = c & 1;
        if (c < 31) { asm volatile("s_waitcnt vmcnt(33)" ::: "memory"); }
        else        { asm volatile("s_waitcnt vmcnt(0)"  ::: "memory"); }
        __builtin_amdgcn_sched_barrier(0);

        const unsigned short* kb = sKb[cur];
        const unsigned* wt = (const unsigned*)(sBlob[cur]);
        const float* dgv = (const float*)(sBlob[cur] + 16384);

        // phase Z: z_i = W[i][:] . u   (lane = i; 4 independent fma chains)
        float z0 = 0.f, z1 = 0.f, z2 = 0.f, z3 = 0.f;
        #pragma unroll
        for (int d2 = 0; d2 < 64; d2 += 2) {
            unsigned wpa = wt[d2 * 64 + lane];
            unsigned wpb = wt[(d2 + 1) * 64 + lane];
            float2 uva = *(const float2*)&sU[d2 * 2];
            float2 uvb = *(const float2*)&sU[d2 * 2 + 2];
            z0 = fmaf(bf2f((unsigned short)(wpa & 0xffff)), uva.x, z0);
            z1 = fmaf(bf2f((unsigned short)(wpa >> 16)),    uva.y, z1);
            z2 = fmaf(bf2f((unsigned short)(wpb & 0xffff)), uvb.x, z2);
            z3 = fmaf(bf2f((unsigned short)(wpb >> 16)),    uvb.y, z3);
        }
        float z  = (z0 + z1) + (z2 + z3);
        float ci = z * dgv[lane];
        sZC[lane * 2]     = z;
        sZC[lane * 2 + 1] = ci;
        // (single wave: compiler inserts the lgkmcnt wait before the reads)

        // phase C: u -= K^T z ; cs += K^T c   (lane owns d = 2*lane, 2*lane+1)
        float du0a = 0.f, du0b = 0.f, du1a = 0.f, du1b = 0.f;
        float dc0a = 0.f, dc0b = 0.f, dc1a = 0.f, dc1b = 0.f;
        #pragma unroll 8
        for (int i = 0; i < 32; ++i) {
            unsigned kp = *(const unsigned*)((const char*)kb + i * 256 + lane * 4);
            float2 zc = *(const float2*)&sZC[i * 2];
            float k0 = bf2f((unsigned short)(kp & 0xffff));
            float k1 = bf2f((unsigned short)(kp >> 16));
            du0a = fmaf(zc.x, k0, du0a); du1a = fmaf(zc.x, k1, du1a);
            dc0a = fmaf(zc.y, k0, dc0a); dc1a = fmaf(zc.y, k1, dc1a);
        }
        #pragma unroll 8
        for (int i = 32; i < 64; ++i) {
            unsigned kp = *(const unsigned*)((const char*)kb + i * 256 + lane * 4);
            float2 zc = *(const float2*)&sZC[i * 2];
            float k0 = bf2f((unsigned short)(kp & 0xffff));
            float k1 = bf2f((unsigned short)(kp >> 16));
            du0b = fmaf(zc.x, k0, du0b); du1b = fmaf(zc.x, k1, du1b);
            dc0b = fmaf(zc.y, k0, dc0b); dc1b = fmaf(zc.y, k1, dc1b);
        }
        sU[lane * 2]     = sU[lane * 2]     - (du0a + du0b);
        sU[lane * 2 + 1] = sU[lane * 2 + 1] - (du1a + du1b);
        csv0 += dc0a + dc0b;
        csv1 += dc1a + dc1b;

        // pin program order: the DMA overwrite of buf[cur] must be issued
        // after phase Z/C's ds_reads of buf[cur] (no barrier = no drain).
        __builtin_amdgcn_sched_barrier(0);
        if (c + 2 < 32) STAGE(cur, c + 2);
        __builtin_amdgcn_sched_barrier(0);
    }
    csb[b * 128 + lane * 2]     = csv0;
    csb[b * 128 + lane * 2 + 1] = csv1;
}

// ---------------- out = cs @ Wo + bo : [64,128]@[128,32000] ----------------
__global__ __launch_bounds__(256) void out_kernel(
    const float* __restrict__ cs, const float* __restrict__ Wo,
    const float* __restrict__ bo, float* __restrict__ out)
{
    __shared__ float sC[64 * 128];
    const int tid = threadIdx.x;
    #pragma unroll
    for (int r = 0; r < 8; ++r)
        ((float4*)sC)[r * 256 + tid] = ((const float4*)cs)[r * 256 + tid];
    __syncthreads();

    const int j = blockIdx.x * 256 + tid;
    float acc[64];
    #pragma unroll
    for (int r = 0; r < 64; ++r) acc[r] = 0.f;
    for (int k0 = 0; k0 < 128; k0 += 4) {
        float w0 = Wo[(size_t)(k0 + 0) * Vv + j];
        float w1 = Wo[(size_t)(k0 + 1) * Vv + j];
        float w2 = Wo[(size_t)(k0 + 2) * Vv + j];
        float w3 = Wo[(size_t)(k0 + 3) * Vv + j];
        #pragma unroll
        for (int r = 0; r < 64; ++r) {
            float4 c = *(const float4*)&sC[r * 128 + k0];
            acc[r] = fmaf(c.x, w0, fmaf(c.y, w1, fmaf(c.z, w2, fmaf(c.w, w3, acc[r]))));
        }
    }
    float bj = bo[j];
    #pragma unroll
    for (int r = 0; r < 64; ++r)
        out[(size_t)r * Vv + j] = acc[r] + bj;
}

extern "C" void kernel_launch(void* const* d_in, const int* in_sizes, int n_in,
                              void* d_out, int out_size, void* d_ws, size_t ws_size,
                              hipStream_t stream)
{
    const int*   seq   = (const int*)  d_in[0];
    const float* embed = (const float*)d_in[1];
    const float* W1    = (const float*)d_in[2];
    const float* b1    = (const float*)d_in[3];
    const float* W2    = (const float*)d_in[4];
    const float* b2    = (const float*)d_in[5];
    const float* gamma = (const float*)d_in[6];
    const float* beta  = (const float*)d_in[7];
    const float* Wp    = (const float*)d_in[8];
    const float* bp    = (const float*)d_in[9];
    const float* Wo    = (const float*)d_in[10];
    const float* bo    = (const float*)d_in[11];
    float* out = (float*)d_out;

    char* wsb = (char*)d_ws;
    unsigned short* ptab = (unsigned short*)(wsb);                 //  8,192,000 B
    char*           SBg  = wsb + 8192000;                          // 35,651,584 B
    unsigned short* W1T  = (unsigned short*)(wsb + 43843584);      //    262,144 B
    unsigned short* W2T  = (unsigned short*)(wsb + 44105728);      //    262,144 B
    unsigned short* WpT  = (unsigned short*)(wsb + 44367872);      //     65,536 B
    float*          csb  = (float*)(wsb + 44433408);               //     32,768 B
    float*          zrow = (float*)(wsb + 44466176);               //        256 B

    prep_kernel<<<576, 256, 0, stream>>>(W1, W2, Wp, W1T, W2T, WpT, zrow);
    enc_kernel<<<Vv / 64, 512, 0, stream>>>(embed, W1T, b1, W2T, b2,
                                            gamma, beta, WpT, bp, ptab);
    sprep_kernel<<<2048, 64, 0, stream>>>(seq, ptab, SBg);
    scan_kernel<<<64, 64, 0, stream>>>(seq, ptab, SBg, zrow, csb);
    out_kernel<<<Vv / 256, 256, 0, stream>>>(csb, Wo, bo, out);
}

// Round 7
// 280.804 us; speedup vs baseline: 11.1475x; 1.1227x over previous
//
#include <hip/hip_runtime.h>

#define Vv 32000
#define Ll 2048

typedef __bf16 bf16x8 __attribute__((ext_vector_type(8)));
typedef float  f32x4  __attribute__((ext_vector_type(4)));

__device__ __forceinline__ unsigned short f2bf(float f) {
    unsigned u = __builtin_bit_cast(unsigned, f);
    u += 0x7fffu + ((u >> 16) & 1u);
    return (unsigned short)(u >> 16);
}
__device__ __forceinline__ float bf2f(unsigned short s) {
    unsigned u = (unsigned)s << 16;
    return __builtin_bit_cast(float, u);
}
__device__ __forceinline__ void unpk8(uint4 v, float* o) {
    o[0] = bf2f((unsigned short)(v.x & 0xffff)); o[1] = bf2f((unsigned short)(v.x >> 16));
    o[2] = bf2f((unsigned short)(v.y & 0xffff)); o[3] = bf2f((unsigned short)(v.y >> 16));
    o[4] = bf2f((unsigned short)(v.z & 0xffff)); o[5] = bf2f((unsigned short)(v.z >> 16));
    o[6] = bf2f((unsigned short)(v.w & 0xffff)); o[7] = bf2f((unsigned short)(v.w >> 16));
}

#define MFMA(a, b, c) __builtin_amdgcn_mfma_f32_16x16x32_bf16(a, b, c, 0, 0, 0)
#define GLL16(gsrc, ldst)                                                    \
    __builtin_amdgcn_global_load_lds(                                        \
        (const __attribute__((address_space(1))) void*)(gsrc),               \
        (__attribute__((address_space(3))) void*)(ldst), 16, 0, 0)
#define GLL4(gsrc, ldst)                                                     \
    __builtin_amdgcn_global_load_lds(                                        \
        (const __attribute__((address_space(1))) void*)(gsrc),               \
        (__attribute__((address_space(3))) void*)(ldst), 4, 0, 0)

// ---------------- prep: transpose W1/W2/Wp to bf16 [N][K]; zero pad row ----
__global__ __launch_bounds__(256) void prep_kernel(
    const float* __restrict__ W1, const float* __restrict__ W2,
    const float* __restrict__ Wp, unsigned short* __restrict__ W1T,
    unsigned short* __restrict__ W2T, unsigned short* __restrict__ WpT,
    float* __restrict__ zrow)
{
    int idx = blockIdx.x * 256 + threadIdx.x;   // pair index
    if (blockIdx.x == 575 && threadIdx.x < 64) zrow[threadIdx.x] = 0.f;
    if (idx < 65536) {                           // W1T [512][256] <- W1 [256][512]
        int e0 = idx * 2, n = e0 >> 8, k = e0 & 255;
        unsigned lo = f2bf(W1[(size_t)k * 512 + n]);
        unsigned hi = f2bf(W1[(size_t)(k + 1) * 512 + n]);
        ((unsigned*)W1T)[idx] = lo | (hi << 16);
    } else if (idx < 131072) {                   // W2T [256][512] <- W2 [512][256]
        int i = idx - 65536, e0 = i * 2, n = e0 >> 9, k = e0 & 511;
        unsigned lo = f2bf(W2[(size_t)k * 256 + n]);
        unsigned hi = f2bf(W2[(size_t)(k + 1) * 256 + n]);
        ((unsigned*)W2T)[i] = lo | (hi << 16);
    } else {                                     // WpT [128][256] <- Wp [256][128]
        int i = idx - 131072, e0 = i * 2, n = e0 >> 8, k = e0 & 255;
        unsigned lo = f2bf(Wp[(size_t)k * 128 + n]);
        unsigned hi = f2bf(Wp[(size_t)(k + 1) * 128 + n]);
        ((unsigned*)WpT)[i] = lo | (hi << 16);
    }
}

// ---------------- fused MFMA encoder over the VOCABULARY (32000 rows) ------
// 512 threads = 8 waves (2 M-groups x 4 N-groups), 64 vocab rows per block.
__global__ __launch_bounds__(512, 4) void enc_kernel(
    const float* __restrict__ embed,
    const unsigned short* __restrict__ W1T, const float* __restrict__ b1,
    const unsigned short* __restrict__ W2T, const float* __restrict__ b2,
    const float* __restrict__ gamma, const float* __restrict__ beta,
    const unsigned short* __restrict__ WpT, const float* __restrict__ bp,
    unsigned short* __restrict__ ptab)
{
    __shared__ char sE[64 * 512];      // bf16 [64][256], XOR-swizzled (e, then h)
    __shared__ char sU[64 * 256];      // bf16 [64][128], swizzled (U chunk) / plain (p stage)
    __shared__ float sPart[64][4][2];
    __shared__ float sMR[64][2];

    const int tid  = threadIdx.x;
    const int lane = tid & 63;
    const int w    = tid >> 6;
    const int wm   = w >> 2;           // 0..1
    const int wn   = w & 3;            // 0..3
    const int l15  = lane & 15;
    const int lk   = lane >> 4;        // 0..3
    const int n0   = blockIdx.x * 64;
    const int r0   = wm * 32;
    const int swl  = (l15 & 7) << 4;   // A-frag row swizzle (row&7 == l15&7)

    // ---- load E tile: identity rows (coalesced), f32 -> bf16 swizzled ----
    #pragma unroll
    for (int cc = 0; cc < 4; ++cc) {
        int c = cc * 512 + tid;          // 0..2047 16B-chunks
        int row  = c >> 5;
        int slot = (c & 31) << 4;
        int kbs  = slot ^ ((row & 7) << 4);
        const float* src = embed + (size_t)(n0 + row) * 256 + (kbs >> 1);
        float4 a = *(const float4*)src;
        float4 b = *(const float4*)(src + 4);
        uint4 pk;
        pk.x = (unsigned)f2bf(a.x) | ((unsigned)f2bf(a.y) << 16);
        pk.y = (unsigned)f2bf(a.z) | ((unsigned)f2bf(a.w) << 16);
        pk.z = (unsigned)f2bf(b.x) | ((unsigned)f2bf(b.y) << 16);
        pk.w = (unsigned)f2bf(b.z) | ((unsigned)f2bf(b.w) << 16);
        *(uint4*)(sE + row * 512 + slot) = pk;
    }
    __syncthreads();

    f32x4 acc2[2][4];
    #pragma unroll
    for (int i = 0; i < 2; ++i)
        #pragma unroll
        for (int j = 0; j < 4; ++j) acc2[i][j] = (f32x4){0.f, 0.f, 0.f, 0.f};

    #pragma unroll 1
    for (int c = 0; c < 4; ++c) {
        // ---- GEMM1 chunk: cols [c*128, c*128+128) ----
        f32x4 acc1[2][2];
        acc1[0][0] = acc1[0][1] = acc1[1][0] = acc1[1][1] = (f32x4){0.f, 0.f, 0.f, 0.f};
        const char* w1p = (const char*)W1T + (size_t)(c * 128 + wn * 32 + l15) * 512 + lk * 16;
        #pragma unroll
        for (int ks = 0; ks < 8; ++ks) {
            int ka = (ks * 64 + lk * 16) ^ swl;
            bf16x8 a0 = *(const bf16x8*)(sE + (r0 + l15) * 512 + ka);
            bf16x8 a1 = *(const bf16x8*)(sE + (r0 + 16 + l15) * 512 + ka);
            bf16x8 b0 = *(const bf16x8*)(w1p + ks * 64);
            bf16x8 b1 = *(const bf16x8*)(w1p + 16 * 512 + ks * 64);
            acc1[0][0] = MFMA(a0, b0, acc1[0][0]);
            acc1[1][0] = MFMA(a1, b0, acc1[1][0]);
            acc1[0][1] = MFMA(a0, b1, acc1[0][1]);
            acc1[1][1] = MFMA(a1, b1, acc1[1][1]);
        }
        float bv0 = b1[c * 128 + wn * 32 + l15];
        float bv1 = b1[c * 128 + wn * 32 + 16 + l15];
        #pragma unroll
        for (int mi = 0; mi < 2; ++mi)
            #pragma unroll
            for (int nj = 0; nj < 2; ++nj) {
                float bv = nj ? bv1 : bv0;
                #pragma unroll
                for (int r = 0; r < 4; ++r) {
                    int row  = r0 + mi * 16 + lk * 4 + r;
                    int coll = wn * 32 + nj * 16 + l15;
                    float v = fmaxf(acc1[mi][nj][r] + bv, 0.f);
                    *(unsigned short*)(sU + row * 256 + ((coll * 2) ^ ((row & 7) << 4))) = f2bf(v);
                }
            }
        __syncthreads();
        // ---- GEMM2 partial: k in [c*128, c*128+128) ----
        const char* w2p = (const char*)W2T + (size_t)(wn * 64 + l15) * 1024 + c * 256 + lk * 16;
        #pragma unroll
        for (int ks = 0; ks < 4; ++ks) {
            int ka = (ks * 64 + lk * 16) ^ swl;
            bf16x8 a0 = *(const bf16x8*)(sU + (r0 + l15) * 256 + ka);
            bf16x8 a1 = *(const bf16x8*)(sU + (r0 + 16 + l15) * 256 + ka);
            #pragma unroll
            for (int nj = 0; nj < 4; ++nj) {
                bf16x8 bb = *(const bf16x8*)(w2p + (size_t)nj * 16 * 1024 + ks * 64);
                acc2[0][nj] = MFMA(a0, bb, acc2[0][nj]);
                acc2[1][nj] = MFMA(a1, bb, acc2[1][nj]);
            }
        }
        __syncthreads();
    }

    // ---- x = e(bf16 from LDS) + f + b2 ; LN stats ----
    float b2v[4], gv[4], btv[4];
    #pragma unroll
    for (int nj = 0; nj < 4; ++nj) {
        int col = wn * 64 + nj * 16 + l15;
        b2v[nj] = b2[col]; gv[nj] = gamma[col]; btv[nj] = beta[col];
    }
    #pragma unroll
    for (int mi = 0; mi < 2; ++mi)
        #pragma unroll
        for (int r = 0; r < 4; ++r) {
            int row = r0 + mi * 16 + lk * 4 + r;
            int swr = (row & 7) << 4;
            float s1 = 0.f, s2 = 0.f;
            #pragma unroll
            for (int nj = 0; nj < 4; ++nj) {
                int col = wn * 64 + nj * 16 + l15;
                float e = bf2f(*(const unsigned short*)(sE + row * 512 + ((col * 2) ^ swr)));
                float x = acc2[mi][nj][r] + b2v[nj] + e;
                acc2[mi][nj][r] = x;
                s1 += x; s2 = fmaf(x, x, s2);
            }
            s1 += __shfl_xor(s1, 1); s2 += __shfl_xor(s2, 1);
            s1 += __shfl_xor(s1, 2); s2 += __shfl_xor(s2, 2);
            s1 += __shfl_xor(s1, 4); s2 += __shfl_xor(s2, 4);
            s1 += __shfl_xor(s1, 8); s2 += __shfl_xor(s2, 8);
            if (l15 == 0) { sPart[row][wn][0] = s1; sPart[row][wn][1] = s2; }
        }
    __syncthreads();
    if (tid < 64) {
        float t1 = sPart[tid][0][0] + sPart[tid][1][0] + sPart[tid][2][0] + sPart[tid][3][0];
        float t2 = sPart[tid][0][1] + sPart[tid][1][1] + sPart[tid][2][1] + sPart[tid][3][1];
        float mu  = t1 * (1.f / 256.f);
        float var = t2 * (1.f / 256.f) - mu * mu;
        sMR[tid][0] = mu;
        sMR[tid][1] = rsqrtf(var + 1e-5f);
    }
    __syncthreads();
    // ---- h -> sE (bf16, swizzled) ----
    #pragma unroll
    for (int mi = 0; mi < 2; ++mi)
        #pragma unroll
        for (int r = 0; r < 4; ++r) {
            int row = r0 + mi * 16 + lk * 4 + r;
            int swr = (row & 7) << 4;
            float mu = sMR[row][0], rs = sMR[row][1];
            #pragma unroll
            for (int nj = 0; nj < 4; ++nj) {
                int col = wn * 64 + nj * 16 + l15;
                float h = (acc2[mi][nj][r] - mu) * rs * gv[nj] + btv[nj];
                *(unsigned short*)(sE + row * 512 + ((col * 2) ^ swr)) = f2bf(h);
            }
        }
    __syncthreads();

    // ---- GEMM3: p = h @ WpT^T + bp ----
    f32x4 acc3[2][2];
    acc3[0][0] = acc3[0][1] = acc3[1][0] = acc3[1][1] = (f32x4){0.f, 0.f, 0.f, 0.f};
    const char* wpp = (const char*)WpT + (size_t)(wn * 32 + l15) * 512 + lk * 16;
    #pragma unroll
    for (int ks = 0; ks < 8; ++ks) {
        int ka = (ks * 64 + lk * 16) ^ swl;
        bf16x8 a0 = *(const bf16x8*)(sE + (r0 + l15) * 512 + ka);
        bf16x8 a1 = *(const bf16x8*)(sE + (r0 + 16 + l15) * 512 + ka);
        bf16x8 b0 = *(const bf16x8*)(wpp + ks * 64);
        bf16x8 b1 = *(const bf16x8*)(wpp + 16 * 512 + ks * 64);
        acc3[0][0] = MFMA(a0, b0, acc3[0][0]);
        acc3[1][0] = MFMA(a1, b0, acc3[1][0]);
        acc3[0][1] = MFMA(a0, b1, acc3[0][1]);
        acc3[1][1] = MFMA(a1, b1, acc3[1][1]);
    }
    float bp0 = bp[wn * 32 + l15], bp1 = bp[wn * 32 + 16 + l15];
    #pragma unroll
    for (int mi = 0; mi < 2; ++mi)
        #pragma unroll
        for (int nj = 0; nj < 2; ++nj)
            #pragma unroll
            for (int r = 0; r < 4; ++r) {
                int row = r0 + mi * 16 + lk * 4 + r;
                int col = wn * 32 + nj * 16 + l15;
                *(unsigned short*)(sU + row * 256 + col * 2) =
                    f2bf(acc3[mi][nj][r] + (nj ? bp1 : bp0));
            }
    __syncthreads();
    #pragma unroll
    for (int ii = 0; ii < 2; ++ii) {
        int idx = tid * 2 + ii;            // 0..1023
        int row = idx >> 4, slot = (idx & 15) << 4;
        *(uint4*)((char*)ptab + (size_t)(n0 + row) * 256 + slot) =
            *(const uint4*)(sU + row * 256 + slot);
    }
}

// ---------------- sprep v3: Gram + block-inverse + W = (D+L)^-1 K ----------
// One wave per (batch, chunk). Blob out (17408 B/chunk):
//   [0,16384): WTP[d2=64][i=64] u32 = packed bf16 pair (W[i][2d2], W[i][2d2+1])
//   [16384, 16640): diag[64] f32 (d_i = G_ii + eps); rest pad.
__global__ __launch_bounds__(64) void sprep_kernel(
    const int* __restrict__ seq, const unsigned short* __restrict__ ptab,
    char* __restrict__ SBg)
{
    __shared__ unsigned short sK[64 * 136];   // 17408 B, rows 272 B
    __shared__ float sG[10 * 16 * 17];        // 10880 B, block-major [q][r][c]
    __shared__ float sM[4 * 16 * 17];         //  4352 B
    __shared__ float sQ[64];                  //   256 B
    __shared__ float sW[64 * 132];            // 33792 B, rows 528 B

    const int blk  = blockIdx.x;              // 0..2047
    const int b    = blk >> 5, ch = blk & 31;
    const int t_hi = 2047 - (ch << 6);
    const int lane = threadIdx.x;
    const int l15  = lane & 15, lk = lane >> 4;

    // ---- stage K rows (lane = row i, t = t_hi - i); zero the query pad ----
    {
        int t = t_hi - lane;
        if (t == 2047) {
            #pragma unroll
            for (int j = 0; j < 16; ++j)
                *(uint4*)((char*)sK + lane * 272 + j * 16) = (uint4){0u, 0u, 0u, 0u};
        } else {
            int v = seq[b * 2048 + t];
            const char* src = (const char*)(ptab + (size_t)v * 128);
            #pragma unroll
            for (int j = 0; j < 16; ++j)
                *(uint4*)((char*)sK + lane * 272 + j * 16) = *(const uint4*)(src + j * 16);
        }
    }
    __syncthreads();

    // ---- Gram lower blocks via MFMA ----
    f32x4 acc[10];
    #pragma unroll
    for (int q = 0; q < 10; ++q) acc[q] = (f32x4){0.f, 0.f, 0.f, 0.f};
    #pragma unroll
    for (int ks = 0; ks < 4; ++ks) {
        bf16x8 fr[4];
        #pragma unroll
        for (int t4 = 0; t4 < 4; ++t4)
            fr[t4] = *(const bf16x8*)((const char*)sK + (t4 * 16 + l15) * 272 + ks * 64 + lk * 16);
        int q = 0;
        #pragma unroll
        for (int ti = 0; ti < 4; ++ti)
            #pragma unroll
            for (int tj = 0; tj <= ti; ++tj, ++q)
                acc[q] = MFMA(fr[ti], fr[tj], acc[q]);
    }
    {
        int q = 0;
        #pragma unroll
        for (int ti = 0; ti < 4; ++ti)
            #pragma unroll
            for (int tj = 0; tj <= ti; ++tj, ++q)
                #pragma unroll
                for (int r = 0; r < 4; ++r)
                    sG[q * 272 + (lk * 4 + r) * 17 + l15] = acc[q][r];
    }
    __syncthreads();

    // ---- reciprocals of diagonal (lane = (g = lk, row = l15)) ----
    {
        int dq = (lk * (lk + 3)) >> 1;            // diag block q-index
        float d = sG[dq * 272 + l15 * 17 + l15] + 1e-6f;
        sQ[lane] = 1.0f / d;
    }
    __syncthreads();

    // ---- invert 4 diagonal blocks: group g = lk, column c = l15 ----
    {
        const int g = lk, c = l15;
        const float* Tg = &sG[((g * (g + 3)) >> 1) * 272];
        float qv[16], av[16], mcol[16];
        #pragma unroll
        for (int r = 0; r < 16; ++r) { qv[r] = sQ[g * 16 + r]; av[r] = 0.f; }
        #pragma unroll
        for (int r = 0; r < 16; ++r) {
            float mr = (((r == c) ? 1.f : 0.f) - av[r]) * qv[r];
            mcol[r] = mr;
            #pragma unroll
            for (int i = r + 1; i < 16; ++i)
                av[i] = fmaf(Tg[i * 17 + r], mr, av[i]);
        }
        #pragma unroll
        for (int r = 0; r < 16; ++r)
            sM[g * 272 + r * 17 + c] = mcol[r];
    }
    __syncthreads();

    // ---- W build: lane = (rr = l15 row-in-block, dqt = lk d-quarter) ----
    const int rr = l15, dqt = lk;
    #pragma unroll 1
    for (int s = 0; s < 4; ++s) {
        float a[32];
        {   // init from K row 16s+rr, cols [dqt*32, +32)
            const char* kr = (const char*)sK + (16 * s + rr) * 272 + dqt * 64;
            #pragma unroll
            for (int v = 0; v < 4; ++v) {
                uint4 kv = *(const uint4*)(kr + v * 16);
                unpk8(kv, &a[v * 8]);
            }
        }
        #pragma unroll
        for (int j = 0; j < 3; ++j) {           // subtract T_sj @ W_j, j < s
            if (j >= s) break;
            const float* Tb = &sG[(((s * (s + 1)) >> 1) + j) * 272];
            #pragma unroll
            for (int m = 0; m < 16; ++m) {
                float t = Tb[rr * 17 + m];
                const float* wrow = &sW[(16 * j + m) * 132 + dqt * 32];
                #pragma unroll
                for (int v = 0; v < 8; ++v) {
                    f32x4 wv = *(const f32x4*)(wrow + v * 4);
                    a[v * 4 + 0] = fmaf(-t, wv.x, a[v * 4 + 0]);
                    a[v * 4 + 1] = fmaf(-t, wv.y, a[v * 4 + 1]);
                    a[v * 4 + 2] = fmaf(-t, wv.z, a[v * 4 + 2]);
                    a[v * 4 + 3] = fmaf(-t, wv.w, a[v * 4 + 3]);
                }
            }
        }
        {   // write tmp rows of block s
            float* wrow = &sW[(16 * s + rr) * 132 + dqt * 32];
            #pragma unroll
            for (int v = 0; v < 8; ++v) {
                f32x4 wv = {a[v * 4 + 0], a[v * 4 + 1], a[v * 4 + 2], a[v * 4 + 3]};
                *(f32x4*)(wrow + v * 4) = wv;
            }
        }
        __syncthreads();
        float o[32];
        #pragma unroll
        for (int v = 0; v < 32; ++v) o[v] = 0.f;
        #pragma unroll
        for (int cc = 0; cc < 16; ++cc) {       // W_s = M_s @ tmp
            float mm = sM[s * 272 + rr * 17 + cc];
            const float* wrow = &sW[(16 * s + cc) * 132 + dqt * 32];
            #pragma unroll
            for (int v = 0; v < 8; ++v) {
                f32x4 wv = *(const f32x4*)(wrow + v * 4);
                o[v * 4 + 0] = fmaf(mm, wv.x, o[v * 4 + 0]);
                o[v * 4 + 1] = fmaf(mm, wv.y, o[v * 4 + 1]);
                o[v * 4 + 2] = fmaf(mm, wv.z, o[v * 4 + 2]);
                o[v * 4 + 3] = fmaf(mm, wv.w, o[v * 4 + 3]);
            }
        }
        __syncthreads();                        // all tmp reads done
        {   // overwrite block-s rows with final W_s
            float* wrow = &sW[(16 * s + rr) * 132 + dqt * 32];
            #pragma unroll
            for (int v = 0; v < 8; ++v) {
                f32x4 wv = {o[v * 4 + 0], o[v * 4 + 1], o[v * 4 + 2], o[v * 4 + 3]};
                *(f32x4*)(wrow + v * 4) = wv;
            }
        }
        __syncthreads();
    }

    // ---- write WTP (transposed, packed bf16) + diag ----
    char* blob = SBg + (size_t)blk * 17408;
    unsigned* wtp = (unsigned*)blob;
    #pragma unroll 8
    for (int d2 = 0; d2 < 64; ++d2) {
        float2 wv = *(const float2*)&sW[lane * 132 + d2 * 2];
        wtp[d2 * 64 + lane] = (unsigned)f2bf(wv.x) | ((unsigned)f2bf(wv.y) << 16);
    }
    {
        int dq = (lk * (lk + 3)) >> 1;
        float d = sG[dq * 272 + l15 * 17 + l15] + 1e-6f;
        *(float*)(blob + 16384 + lane * 4) = d;
    }
}

// ---------------- serial chunked scan v2: 8-wave cooperative chunk body ----
// 512 threads / block, one block per batch. Raw s_barrier only (no
// __syncthreads in the loop: it would drain vmcnt and kill the DMA
// double-buffer). u lives in registers (pair per lane, replicated per wave).
__global__ __launch_bounds__(512) void scan_kernel(
    const int* __restrict__ seq, const unsigned short* __restrict__ ptab,
    const char* __restrict__ SBg, const float* __restrict__ zrow,
    float* __restrict__ csb)
{
    __shared__ int sSeq[2048];
    __shared__ unsigned short sKb[2][8192];      // [64][128] bf16, linear
    __shared__ __align__(16) char sBlob[2][16640]; // WTP 16K + diag 256B
    __shared__ float  sPZ[8][64];                // per-wave z partials
    __shared__ float2 sPC[8][64];                // per-wave du partials / csv

    const int b    = blockIdx.x;
    const int tid  = threadIdx.x;
    const int lane = tid & 63;
    const int w    = tid >> 6;

    *(int4*)&sSeq[tid * 4] = *(const int4*)&seq[b * 2048 + tid * 4];
    float u0, u1;                                // u pair (2*lane, 2*lane+1)
    {
        int vq = seq[b * 2048 + 2047];
        unsigned pk = *(const unsigned*)(ptab + (size_t)vq * 128 + lane * 2);
        u0 = bf2f((unsigned short)(pk & 0xffff));
        u1 = bf2f((unsigned short)(pk >> 16));
    }
    float csv0 = 0.f, csv1 = 0.f;
    __syncthreads();            // once: sSeq visible (drains vmcnt, harmless here)

    auto STAGE = [&](int s, int ch) {            // 4 GLLs/wave (wave 7: 5)
        int t_hi = 2047 - (ch << 6);
        #pragma unroll
        for (int kk = 0; kk < 2; ++kk) {
            int k = w * 2 + kk;
            int g = k * 64 + lane;
            int r = g >> 4, sd = g & 15;
            int t = t_hi - r;
            int v = sSeq[t];
            const char* srow = (t == 2047) ? (const char*)zrow
                                           : (const char*)(ptab + (size_t)v * 128);
            GLL16(srow + sd * 16, (char*)sKb[s] + k * 1024);
        }
        const char* bsrc = SBg + ((size_t)b * 32 + ch) * 17408;
        #pragma unroll
        for (int kk = 0; kk < 2; ++kk) {
            int k = w * 2 + kk;
            GLL16(bsrc + k * 1024 + lane * 16, (char*)sBlob[s] + k * 1024);
        }
        if (w == 7)
            GLL4(bsrc + 16384 + lane * 4, (char*)sBlob[s] + 16384);
    };

    STAGE(0, 0); STAGE(1, 1);

    #pragma unroll 1
    for (int c = 0; c < 32; ++c) {
        const int cur = c & 1;
        if (c < 31) {
            if (w == 7) asm volatile("s_waitcnt vmcnt(5)" ::: "memory");
            else        asm volatile("s_waitcnt vmcnt(4)" ::: "memory");
        } else {
            asm volatile("s_waitcnt vmcnt(0)" ::: "memory");
        }
        __builtin_amdgcn_s_barrier();            // B0: all waves' DMA landed
        __builtin_amdgcn_sched_barrier(0);

        const unsigned short* kb = sKb[cur];
        const unsigned* wt = (const unsigned*)(sBlob[cur]);
        const float* dgv = (const float*)(sBlob[cur] + 16384);

        // phase Z partial: wave w covers d2 in [8w, 8w+8); lane = i
        float zp = 0.f;
        #pragma unroll
        for (int j = 0; j < 8; ++j) {
            int d2 = w * 8 + j;
            unsigned wp = wt[d2 * 64 + lane];    // conflict-free
            float ua = __shfl(u0, d2);
            float ub = __shfl(u1, d2);
            zp = fmaf(bf2f((unsigned short)(wp & 0xffff)), ua, zp);
            zp = fmaf(bf2f((unsigned short)(wp >> 16)),    ub, zp);
        }
        sPZ[w][lane] = zp;
        asm volatile("s_waitcnt lgkmcnt(0)" ::: "memory");
        __builtin_amdgcn_s_barrier();            // B1
        __builtin_amdgcn_sched_barrier(0);

        // redundant full reduce (identical order in every wave) -> z, ci
        float z = 0.f;
        #pragma unroll
        for (int ww = 0; ww < 8; ++ww) z += sPZ[ww][lane];
        float ci = z * dgv[lane];

        // phase C partial: wave w covers i in [8w, 8w+8); lane = d-pair
        float du0 = 0.f, du1 = 0.f;
        #pragma unroll
        for (int j = 0; j < 8; ++j) {
            int i = w * 8 + j;
            float zi  = __shfl(z, i);
            float cii = __shfl(ci, i);
            unsigned kp = *(const unsigned*)((const char*)kb + i * 256 + lane * 4);
            float k0 = bf2f((unsigned short)(kp & 0xffff));
            float k1 = bf2f((unsigned short)(kp >> 16));
            du0  = fmaf(zi,  k0, du0);  du1  = fmaf(zi,  k1, du1);
            csv0 = fmaf(cii, k0, csv0); csv1 = fmaf(cii, k1, csv1);
        }
        sPC[w][lane] = make_float2(du0, du1);
        asm volatile("s_waitcnt lgkmcnt(0)" ::: "memory");
        __builtin_amdgcn_s_barrier();            // B2: buf cur fully consumed
        __builtin_amdgcn_sched_barrier(0);

        if (c + 2 < 32) STAGE(cur, c + 2);       // overwrite is now safe

        float s0 = 0.f, s1 = 0.f;
        #pragma unroll
        for (int ww = 0; ww < 8; ++ww) {
            float2 p = sPC[ww][lane];
            s0 += p.x; s1 += p.y;
        }
        u0 -= s0; u1 -= s1;
    }

    // final csv reduce across waves
    asm volatile("s_waitcnt lgkmcnt(0)" ::: "memory");
    __builtin_amdgcn_s_barrier();                // all u-update reads done
    sPC[w][lane] = make_float2(csv0, csv1);
    asm volatile("s_waitcnt lgkmcnt(0)" ::: "memory");
    __builtin_amdgcn_s_barrier();
    if (w == 0) {
        float a0 = 0.f, a1 = 0.f;
        #pragma unroll
        for (int ww = 0; ww < 8; ++ww) {
            float2 p = sPC[ww][lane];
            a0 += p.x; a1 += p.y;
        }
        csb[b * 128 + lane * 2]     = a0;
        csb[b * 128 + lane * 2 + 1] = a1;
    }
}

// ---------------- out = cs @ Wo + bo : [64,128]@[128,32000] ----------------
__global__ __launch_bounds__(256) void out_kernel(
    const float* __restrict__ cs, const float* __restrict__ Wo,
    const float* __restrict__ bo, float* __restrict__ out)
{
    __shared__ float sC[64 * 128];
    const int tid = threadIdx.x;
    #pragma unroll
    for (int r = 0; r < 8; ++r)
        ((float4*)sC)[r * 256 + tid] = ((const float4*)cs)[r * 256 + tid];
    __syncthreads();

    const int j = blockIdx.x * 256 + tid;
    float acc[64];
    #pragma unroll
    for (int r = 0; r < 64; ++r) acc[r] = 0.f;
    for (int k0 = 0; k0 < 128; k0 += 4) {
        float w0 = Wo[(size_t)(k0 + 0) * Vv + j];
        float w1 = Wo[(size_t)(k0 + 1) * Vv + j];
        float w2 = Wo[(size_t)(k0 + 2) * Vv + j];
        float w3 = Wo[(size_t)(k0 + 3) * Vv + j];
        #pragma unroll
        for (int r = 0; r < 64; ++r) {
            float4 c = *(const float4*)&sC[r * 128 + k0];
            acc[r] = fmaf(c.x, w0, fmaf(c.y, w1, fmaf(c.z, w2, fmaf(c.w, w3, acc[r]))));
        }
    }
    float bj = bo[j];
    #pragma unroll
    for (int r = 0; r < 64; ++r)
        out[(size_t)r * Vv + j] = acc[r] + bj;
}

extern "C" void kernel_launch(void* const* d_in, const int* in_sizes, int n_in,
                              void* d_out, int out_size, void* d_ws, size_t ws_size,
                              hipStream_t stream)
{
    const int*   seq   = (const int*)  d_in[0];
    const float* embed = (const float*)d_in[1];
    const float* W1    = (const float*)d_in[2];
    const float* b1    = (const float*)d_in[3];
    const float* W2    = (const float*)d_in[4];
    const float* b2    = (const float*)d_in[5];
    const float* gamma = (const float*)d_in[6];
    const float* beta  = (const float*)d_in[7];
    const float* Wp    = (const float*)d_in[8];
    const float* bp    = (const float*)d_in[9];
    const float* Wo    = (const float*)d_in[10];
    const float* bo    = (const float*)d_in[11];
    float* out = (float*)d_out;

    char* wsb = (char*)d_ws;
    unsigned short* ptab = (unsigned short*)(wsb);                 //  8,192,000 B
    char*           SBg  = wsb + 8192000;                          // 35,651,584 B
    unsigned short* W1T  = (unsigned short*)(wsb + 43843584);      //    262,144 B
    unsigned short* W2T  = (unsigned short*)(wsb + 44105728);      //    262,144 B
    unsigned short* WpT  = (unsigned short*)(wsb + 44367872);      //     65,536 B
    float*          csb  = (float*)(wsb + 44433408);               //     32,768 B
    float*          zrow = (float*)(wsb + 44466176);               //        256 B

    prep_kernel<<<576, 256, 0, stream>>>(W1, W2, Wp, W1T, W2T, WpT, zrow);
    enc_kernel<<<Vv / 64, 512, 0, stream>>>(embed, W1T, b1, W2T, b2,
                                            gamma, beta, WpT, bp, ptab);
    sprep_kernel<<<2048, 64, 0, stream>>>(seq, ptab, SBg);
    scan_kernel<<<64, 512, 0, stream>>>(seq, ptab, SBg, zrow, csb);
    out_kernel<<<Vv / 256, 256, 0, stream>>>(csb, Wo, bo, out);
}